// Round 12
// baseline (4971.759 us; speedup 1.0000x reference)
//
#include <hip/hip_runtime.h>
#include <cmath>

#define NB 64
#define NP 196
#define NE 2048
#define NV 10000
#define NL 52
#define NT 51

typedef unsigned short bf16_t;
typedef __attribute__((ext_vector_type(8))) short bf16x8;
typedef __attribute__((ext_vector_type(4))) float f32x4;

__device__ inline unsigned short f2bf(float f){
  unsigned int x = __float_as_uint(f);
  unsigned int r = x + 0x7fffu + ((x>>16)&1u);
  return (unsigned short)(r>>16);
}
__device__ inline float bf2f(unsigned short u){ return __uint_as_float(((unsigned int)u)<<16); }
__device__ inline float sigm(float x){ return 1.f/(1.f+expf(-x)); }

// ---------------- sort + nact + zero flags ----------------
__global__ void k_sort(const int* __restrict__ cap_len, const int* __restrict__ caps,
                       int* __restrict__ order, int* __restrict__ dlen, int* __restrict__ caps_s,
                       int* __restrict__ nact, int* __restrict__ flags,
                       float* __restrict__ out_caps, float* __restrict__ out_dlen, float* __restrict__ out_order){
  __shared__ int len_s[NB];
  __shared__ int ord_s[NB];
  __shared__ int dls[NB];
  int t = threadIdx.x; // 64 threads
  // zero all flags (51*64 eflags + 64 gflags)
  for(int i=t; i<NT*64+64; i+=64) flags[i] = 0;
  len_s[t] = cap_len[t];
  __syncthreads();
  int li = len_s[t]; int rank = 0;
  for(int j=0;j<NB;j++){ int lj = len_s[j]; rank += ((lj > li) || (lj==li && j<t)) ? 1 : 0; }
  ord_s[rank] = t;
  __syncthreads();
  int ob = ord_s[t];
  order[t] = ob; out_order[t] = (float)ob;
  int ls = len_s[ob]; dlen[t] = ls-1; out_dlen[t] = (float)(ls-1); dls[t] = ls-1;
  for(int l=0;l<NL;l++){ int cv = caps[ob*NL + l]; caps_s[t*NL+l]=cv; out_caps[t*NL+l] = (float)cv; }
  __syncthreads();
  if(t < NT){
    int cnt=0;
    for(int b=0;b<NB;b++) cnt += (dls[b] > t) ? 1 : 0;
    nact[t] = cnt;
  }
}

// ---------------- f32 -> bf16 converters ----------------
__global__ __launch_bounds__(256) void k_cvt4(const float* __restrict__ src, bf16_t* __restrict__ dst, int n4){
  int i = blockIdx.x*blockDim.x + threadIdx.x;
  int stride = gridDim.x*blockDim.x;
  for(; i<n4; i+=stride){
    float4 v = ((const float4*)src)[i];
    unsigned long long p = (unsigned long long)f2bf(v.x)
        | ((unsigned long long)f2bf(v.y)<<16)
        | ((unsigned long long)f2bf(v.z)<<32)
        | ((unsigned long long)f2bf(v.w)<<48);
    ((unsigned long long*)dst)[i] = p;
  }
}

__global__ __launch_bounds__(256) void k_cvt2d4(const float* __restrict__ src, int rows, int cols,
                                                bf16_t* __restrict__ dst, int dld, int doff){
  int n4 = rows*cols/4;
  int c4n = cols/4;
  int i = blockIdx.x*blockDim.x + threadIdx.x;
  int stride = gridDim.x*blockDim.x;
  for(; i<n4; i+=stride){
    int r = i / c4n, c4 = i % c4n;
    float4 v = ((const float4*)src)[i];
    unsigned long long p = (unsigned long long)f2bf(v.x)
        | ((unsigned long long)f2bf(v.y)<<16)
        | ((unsigned long long)f2bf(v.z)<<32)
        | ((unsigned long long)f2bf(v.w)<<48);
    *(unsigned long long*)(dst + (size_t)r*dld + doff + c4*4) = p;
  }
}

// ---------------- mean over P from bf16 enc ----------------
__global__ __launch_bounds__(256) void k_mean(const bf16_t* __restrict__ encb, const int* __restrict__ order,
                                              bf16_t* __restrict__ me_s){
  int bs = blockIdx.x; int ec = blockIdx.y; int e = ec*256 + threadIdx.x;
  int ob = order[bs];
  const bf16_t* p = encb + (size_t)ob*NP*NE + e;
  float acc=0.f;
  for(int q=0;q<NP;q++) acc += bf2f(p[(size_t)q*NE]);
  me_s[(size_t)bs*NE + e] = f2bf(acc * (1.0f/NP));
}

// ---------------- embedding precompute: embAll[t][b][512] ----------------
__global__ __launch_bounds__(256) void k_emb(const int* __restrict__ caps_s, const float* __restrict__ emb_table,
                                             bf16_t* __restrict__ embAll){
  int b = blockIdx.x, t = blockIdx.y, tid = threadIdx.x;
  int cap = caps_s[b*NL + t];
  bf16_t* dst = embAll + ((size_t)t*NB + b)*512;
  const float* src = emb_table + (size_t)cap*512;
  dst[tid]       = f2bf(src[tid]);
  dst[tid + 256] = f2bf(src[tid + 256]);
}

// ---------------- big GEMM (128x128 tiles), XCD-swizzled 1D grid ----------------
template<int MODE>
__global__ __launch_bounds__(256) void k_big(const bf16_t* __restrict__ A, int lda, int Kdim,
      const bf16_t* __restrict__ Bw, int nrowsB,
      const float* __restrict__ bias, float* __restrict__ outf, bf16_t* __restrict__ outb,
      const int* __restrict__ dlen){
  __shared__ __align__(16) char smem_raw[36864];
  bf16_t (*As)[72] = (bf16_t(*)[72])smem_raw;
  bf16_t (*Bs)[72] = (bf16_t(*)[72])(smem_raw + 18432);
  int lid = blockIdx.x;
  int nblk, mblk;
  if(MODE==0){
    int wg = (lid&7)*49 + (lid>>3);     // 392/8 = 49 exact
    mblk = wg>>2; nblk = wg&3;
  } else {
    int xcd = lid&7; int idx = lid>>3;  // 2054 = 8*256 + 6
    int wg = (xcd<6) ? xcd*257 + idx : 1542 + (xcd-6)*256 + idx;
    nblk = wg/26; mblk = wg - nblk*26;
  }
  int tid = threadIdx.x;
  int w = tid>>6, l = tid&63;
  int moff = (w>>1)*64, noff = (w&1)*64;
  f32x4 acc[4][4] = {};
  const int mbase = mblk*128, nbase = nblk*128;
  for(int k0=0; k0<Kdim; k0+=64){
    __syncthreads();
    for(int u=0;u<4;u++){
      int lin = u*256 + tid; int row = lin>>3; int col = (lin&7)*8;
      *(bf16x8*)(&As[row][col]) = *(const bf16x8*)(A + (size_t)(mbase+row)*lda + k0 + col);
      int rB = nbase+row; if(MODE==2 && rB >= nrowsB) rB = nrowsB-1;
      *(bf16x8*)(&Bs[row][col]) = *(const bf16x8*)(Bw + (size_t)rB*lda + k0 + col);
    }
    __syncthreads();
    for(int kk=0;kk<2;kk++){
      bf16x8 af[4], bfr[4];
      for(int m=0;m<4;m++) af[m] = *(bf16x8*)(&As[moff + 16*m + (l&15)][kk*32 + (l>>4)*8]);
      for(int n=0;n<4;n++) bfr[n] = *(bf16x8*)(&Bs[noff + 16*n + (l&15)][kk*32 + (l>>4)*8]);
      for(int m=0;m<4;m++)
        for(int n=0;n<4;n++)
          acc[m][n] = __builtin_amdgcn_mfma_f32_16x16x32_bf16(af[m], bfr[n], acc[m][n], 0,0,0);
    }
  }
  if(MODE==0){
    for(int m=0;m<4;m++) for(int n=0;n<4;n++){
      int col = nbase + noff + 16*n + (l&15);
      float bi = bias[col];
      for(int r=0;r<4;r++){
        int row = mbase + moff + 16*m + (l>>4)*4 + r;
        outb[(size_t)row*512 + col] = f2bf(acc[m][n][r] + bi);
      }
    }
  } else {
    float* st = (float*)smem_raw;  // 64*128*4 = 32768 <= 36864
    for(int h=0; h<2; ++h){
      __syncthreads();
      if((w>>1)==h){
        for(int m=0;m<4;m++) for(int n=0;n<4;n++)
          for(int r=0;r<4;r++)
            st[(16*m + (l>>4)*4 + r)*128 + noff + 16*n + (l&15)] = acc[m][n][r];
      }
      __syncthreads();
      for(int rr = tid>>5; rr<64; rr+=8){
        int row = mbase + h*64 + rr;
        if(row < NT*NB){
          int tt = row>>6, bb = row&63;
          int cc = (tid&31)*4;
          int col0 = nbase + cc;
          if(col0 < NV){
            float4 v = *(float4*)&st[rr*128 + cc];
            float4 bi4 = *(const float4*)&bias[col0];
            v.x+=bi4.x; v.y+=bi4.y; v.z+=bi4.z; v.w+=bi4.w;
            if(tt >= dlen[bb]){ v.x=0.f; v.y=0.f; v.z=0.f; v.w=0.f; }
            *(float4*)&outf[((size_t)bb*NT + tt)*NV + col0] = v;
          }
        }
      }
    }
  }
}

// ---------------- small-M (64) GEMM with K-split: partials ----------------
template<int KSL>
__global__ __launch_bounds__(256) void k_gemm_part(const bf16_t* __restrict__ Ax, int lda,
        const bf16_t* __restrict__ W, int ldw, float* __restrict__ part, int N){
  __shared__ bf16_t As[64][KSL+8];
  int ntile = blockIdx.x, ks = blockIdx.y;
  int tid = threadIdx.x; int w = tid>>6, l = tid&63;
  int k0 = ks*KSL;
  constexpr int UPR = KSL/8;
  constexpr int UPT = 64*UPR/256;
  for(int u=0;u<UPT;u++){
    int lin = u*256 + tid; int row = lin/UPR; int col = (lin%UPR)*8;
    *(bf16x8*)(&As[row][col]) = *(const bf16x8*)(Ax + (size_t)row*lda + k0 + col);
  }
  __syncthreads();
  f32x4 acc[4][4] = {};
  int nbase = ntile*256 + w*64;
  for(int kk=0; kk<KSL/32; kk++){
    bf16x8 af[4], bfr[4];
    for(int m=0;m<4;m++) af[m] = *(bf16x8*)(&As[16*m + (l&15)][kk*32 + (l>>4)*8]);
    for(int n=0;n<4;n++) bfr[n] = *(const bf16x8*)(W + (size_t)(nbase + 16*n + (l&15))*ldw + k0 + kk*32 + (l>>4)*8);
    for(int m=0;m<4;m++)
      for(int n=0;n<4;n++)
        acc[m][n] = __builtin_amdgcn_mfma_f32_16x16x32_bf16(af[m], bfr[n], acc[m][n], 0,0,0);
  }
  float* po = part + (size_t)ks*64*N;
  for(int m=0;m<4;m++) for(int n=0;n<4;n++){
    int col = nbase + 16*n + (l&15);
    for(int r=0;r<4;r++){
      int row = 16*m + (l>>4)*4 + r;
      po[(size_t)row*N + col] = acc[m][n][r];
    }
  }
}

// ---------------- combine init partials -> h0 (hbuf0), c0 ----------------
__global__ __launch_bounds__(256) void k_init_fin(const float* __restrict__ part,
        const float* __restrict__ b_ih_, const float* __restrict__ b_ic_,
        float* __restrict__ c, bf16_t* __restrict__ h0){
  int idx = blockIdx.x*256 + threadIdx.x;  // 0..32767
  int b_ = idx>>9, d = idx&511;
  float h = b_ih_[d], cc = b_ic_[d];
  for(int ks=0;ks<4;ks++){
    const float* p = part + (size_t)ks*64*1024 + (size_t)b_*1024;
    h += p[d]; cc += p[512+d];
  }
  c[idx] = cc;
  h0[(size_t)b_*512 + d] = f2bf(h);
}

// ---------------- Kernel A: fused {e-scores | softmax+awe+gate} via per-b flag ----------------
// grid (64 b, 8): y<4 -> e role (pg=y, R8 k_e geometry); y>=4 -> awe role (slice=y-4, R8 k_awe geometry)
__global__ __launch_bounds__(256) void k_att(const bf16_t* __restrict__ att1,
    const bf16_t* __restrict__ enc,
    const float* __restrict__ a2g, const float* __restrict__ b_da, const float* __restrict__ b_fb,
    const float* __restrict__ w_fa, const float* __restrict__ b_fa,
    const int* __restrict__ order, const int* __restrict__ nact,
    float* __restrict__ e_out, float* __restrict__ alphas_out, bf16_t* __restrict__ xh_awe,
    int* __restrict__ eflags, int t){
  int b_ = blockIdx.x, role = blockIdx.y, tid = threadIdx.x;
  int w = tid>>6, l = tid&63;
  int* flag = eflags + b_;
  if(role < 4){
    // ---- e role: pg = role ----
    if(b_ >= nact[t]) return;
    int pg = role;
    const float* pa0 = a2g + ((size_t)0*NB + b_)*2560;
    const float* pa1 = a2g + ((size_t)1*NB + b_)*2560;
    const float* pa2 = a2g + ((size_t)2*NB + b_)*2560;
    const float* pa3 = a2g + ((size_t)3*NB + b_)*2560;
    float ar[8], wr[8];
    #pragma unroll
    for(int q=0;q<8;q++){
      int i = l*8 + q;
      ar[q] = pa0[i] + pa1[i] + pa2[i] + pa3[i] + b_da[i];
      wr[q] = w_fa[i];
    }
    float bfa0 = b_fa[0];
    int ob = order[b_];
    for(int pl=w; pl<49; pl+=4){
      int p = pg*49 + pl;
      bf16x8 a1v = *(const bf16x8*)(att1 + ((size_t)ob*NP + p)*512 + l*8);
      float s = 0.f;
      #pragma unroll
      for(int q=0;q<8;q++){
        float v = bf2f((unsigned short)a1v[q]) + ar[q];
        v = v>0.f ? v : 0.f;
        s += v*wr[q];
      }
      #pragma unroll
      for(int off=32;off;off>>=1) s += __shfl_down(s, off);
      if(l==0) e_out[b_*NP + p] = s + bfa0;
    }
    __syncthreads();                 // drain this block's e_out stores
    if(tid==0){
      __threadfence();               // release: make visible device-wide
      __hip_atomic_fetch_add(flag, 1, __ATOMIC_RELEASE, __HIP_MEMORY_SCOPE_AGENT);
    }
  } else {
    // ---- awe role: y = role-4 ----
    int y = role - 4;
    if(b_ >= nact[t]){
      if(y==0 && tid<NP) alphas_out[((size_t)b_*NT + t)*NP + tid] = 0.f;
      return;
    }
    if(tid==0){
      while(__hip_atomic_load(flag, __ATOMIC_ACQUIRE, __HIP_MEMORY_SCOPE_AGENT) < 4)
        __builtin_amdgcn_s_sleep(2);
    }
    __syncthreads();
    __threadfence();                 // acquire: invalidate stale cache
    __shared__ float al[200];
    __shared__ float red[8];
    __shared__ float aw[4][512];
    float v = (tid<NP)? e_out[b_*NP + tid] : -1e30f;
    float m = v;
    #pragma unroll
    for(int off=32;off;off>>=1) m = fmaxf(m, __shfl_down(m, off));
    if(l==0) red[w] = m;
    __syncthreads();
    float mx = fmaxf(fmaxf(red[0],red[1]), fmaxf(red[2],red[3]));
    float ex = (tid<NP)? expf(v - mx) : 0.f;
    float s2 = ex;
    #pragma unroll
    for(int off=32;off;off>>=1) s2 += __shfl_down(s2, off);
    if(l==0) red[4+w] = s2;
    __syncthreads();
    float inv = 1.f/(red[4]+red[5]+red[6]+red[7]);
    if(tid<NP){
      float a = ex*inv;
      al[tid] = a;
      if(y==0) alphas_out[((size_t)b_*NT + t)*NP + tid] = a;
    }
    __syncthreads();
    int ob = order[b_];
    int j0 = y*512 + l*8;
    float a8[8] = {};
    const bf16_t* ep = enc + (size_t)ob*NP*NE + j0;
    int p0 = w*49;
    #pragma unroll 4
    for(int pp=0; pp<49; ++pp){
      int p = p0 + pp;
      bf16x8 ev = *(const bf16x8*)(ep + (size_t)p*NE);
      float alp = al[p];
      #pragma unroll
      for(int q=0;q<8;q++) a8[q] += alp*bf2f((unsigned short)ev[q]);
    }
    #pragma unroll
    for(int q=0;q<8;q++) aw[w][l*8 + q] = a8[q];
    __syncthreads();
    const float* pa0 = a2g + ((size_t)0*NB + b_)*2560;
    const float* pa1 = a2g + ((size_t)1*NB + b_)*2560;
    const float* pa2 = a2g + ((size_t)2*NB + b_)*2560;
    const float* pa3 = a2g + ((size_t)3*NB + b_)*2560;
    int jl = tid*2;
    int j  = y*512 + jl;
    #pragma unroll
    for(int q=0;q<2;q++){
      float s = aw[0][jl+q] + aw[1][jl+q] + aw[2][jl+q] + aw[3][jl+q];
      int jj = 512 + j + q;
      float gpre = pa0[jj] + pa1[jj] + pa2[jj] + pa3[jj] + b_fb[j + q];
      xh_awe[(size_t)b_*2048 + j + q] = f2bf(sigm(gpre)*s);
    }
  }
}

// ---------------- Kernel B: fused {gates GEMM + cell | a2g partials} via global flag ----------------
// grid 168: blk<128 gatecell (R8 geometry); blk>=128 a2g = k_gemm_part<128> on hw (40 blocks)
__global__ __launch_bounds__(256) void k_cell(const bf16_t* __restrict__ embT,
    const bf16_t* __restrict__ xh_awe, const bf16_t* __restrict__ hr,
    bf16_t* __restrict__ hw, const bf16_t* __restrict__ Wcat,
    const float* __restrict__ b_ih, const float* __restrict__ b_hh,
    float* __restrict__ cbuf, bf16_t* __restrict__ h2all,
    const bf16_t* __restrict__ Wdafb, float* __restrict__ a2gp,
    const int* __restrict__ dlen, int* __restrict__ gflag, int t){
  int blk = blockIdx.x, tid = threadIdx.x;
  int w = tid>>6, l = tid&63;
  if(blk < 128){
    __shared__ float part[4][64][16];
    int j = blk;
    int n_ = l&15;
    int wrow = (n_>>2)*512 + j*4 + (n_&3);
    const bf16_t* wp = Wcat + (size_t)wrow*3072;
    f32x4 acc[4] = {};
    int k0w = w*768;
    for(int kk=0;kk<24;kk++){
      int col = k0w + kk*32 + (l>>4)*8;
      bf16x8 af[4], bg;
      if(col < 512){
        #pragma unroll
        for(int m=0;m<4;m++) af[m] = *(const bf16x8*)(embT + (size_t)(16*m + n_)*512 + col);
      } else if(col < 2560){
        #pragma unroll
        for(int m=0;m<4;m++) af[m] = *(const bf16x8*)(xh_awe + (size_t)(16*m + n_)*2048 + col - 512);
      } else {
        #pragma unroll
        for(int m=0;m<4;m++) af[m] = *(const bf16x8*)(hr + (size_t)(16*m + n_)*512 + col - 2560);
      }
      bg = *(const bf16x8*)(wp + col);
      #pragma unroll
      for(int m=0;m<4;m++)
        acc[m] = __builtin_amdgcn_mfma_f32_16x16x32_bf16(af[m], bg, acc[m], 0,0,0);
    }
    #pragma unroll
    for(int m=0;m<4;m++)
      #pragma unroll
      for(int r=0;r<4;r++)
        part[w][16*m + (l>>4)*4 + r][n_] = acc[m][r];
    __syncthreads();
    int b = tid>>2, c = tid&3;
    int dg = j*4 + c;
    float gs[4];
    #pragma unroll
    for(int g=0;g<4;g++){
      gs[g] = b_ih[g*512+dg] + b_hh[g*512+dg]
            + part[0][b][g*4+c] + part[1][b][g*4+c]
            + part[2][b][g*4+c] + part[3][b][g*4+c];
    }
    float oldc = cbuf[b*512 + dg];
    float c2 = sigm(gs[1])*oldc + sigm(gs[0])*tanhf(gs[2]);
    float h2 = sigm(gs[3])*tanhf(c2);
    bool mk = t < dlen[b];
    if(mk) cbuf[b*512 + dg] = c2;
    hw[(size_t)b*512 + dg] = mk ? f2bf(h2) : hr[(size_t)b*512 + dg];
    h2all[((size_t)t*NB + b)*512 + dg] = f2bf(h2);
    __syncthreads();                 // drain hw stores
    if(tid==0){
      __threadfence();
      __hip_atomic_fetch_add(gflag, 1, __ATOMIC_RELEASE, __HIP_MEMORY_SCOPE_AGENT);
    }
  } else {
    // a2g role: ntile/ks from blk-128 (40 blocks = 10 ntile x 4 ks), KSL=128
    if(tid==0){
      while(__hip_atomic_load(gflag, __ATOMIC_ACQUIRE, __HIP_MEMORY_SCOPE_AGENT) < 128)
        __builtin_amdgcn_s_sleep(2);
    }
    __syncthreads();
    __threadfence();
    __shared__ bf16_t As[64][136];
    int bb = blk - 128;
    int ntile = bb % 10, ks = bb / 10;
    int k0 = ks*128;
    for(int u=0;u<4;u++){
      int lin = u*256 + tid; int row = lin>>4; int col = (lin&15)*8;
      *(bf16x8*)(&As[row][col]) = *(const bf16x8*)(hw + (size_t)row*512 + k0 + col);
    }
    __syncthreads();
    f32x4 acc[4][4] = {};
    int nbase = ntile*256 + w*64;
    for(int kk=0; kk<4; kk++){
      bf16x8 af[4], bfr[4];
      for(int m=0;m<4;m++) af[m] = *(bf16x8*)(&As[16*m + (l&15)][kk*32 + (l>>4)*8]);
      for(int n=0;n<4;n++) bfr[n] = *(const bf16x8*)(Wdafb + (size_t)(nbase + 16*n + (l&15))*512 + k0 + kk*32 + (l>>4)*8);
      for(int m=0;m<4;m++)
        for(int n=0;n<4;n++)
          acc[m][n] = __builtin_amdgcn_mfma_f32_16x16x32_bf16(af[m], bfr[n], acc[m][n], 0,0,0);
    }
    float* po = a2gp + (size_t)ks*64*2560;
    for(int m=0;m<4;m++) for(int n=0;n<4;n++){
      int col = nbase + 16*n + (l&15);
      for(int r=0;r<4;r++){
        int row = 16*m + (l>>4)*4 + r;
        po[(size_t)row*2560 + col] = acc[m][n][r];
      }
    }
  }
}

// ---------------- launcher ----------------
extern "C" void kernel_launch(void* const* d_in, const int* in_sizes, int n_in,
                              void* d_out, int out_size, void* d_ws, size_t ws_size,
                              hipStream_t stream){
  (void)in_sizes; (void)n_in; (void)out_size; (void)ws_size;
  const float* encoder_out      = (const float*)d_in[0];
  const int*   encoded_captions = (const int*)d_in[1];
  const int*   caption_lengths  = (const int*)d_in[2];
  const float* W_ea = (const float*)d_in[3];  const float* b_ea = (const float*)d_in[4];
  const float* W_da = (const float*)d_in[5];  const float* b_da = (const float*)d_in[6];
  const float* w_fa = (const float*)d_in[7];  const float* b_fa = (const float*)d_in[8];
  const float* emb_table = (const float*)d_in[9];
  const float* W_ih = (const float*)d_in[10]; const float* b_ih = (const float*)d_in[11];
  const float* W_hh = (const float*)d_in[12]; const float* b_hh = (const float*)d_in[13];
  const float* W_init_h = (const float*)d_in[14]; const float* b_init_h = (const float*)d_in[15];
  const float* W_init_c = (const float*)d_in[16]; const float* b_init_c = (const float*)d_in[17];
  const float* W_fb = (const float*)d_in[18]; const float* b_fb = (const float*)d_in[19];
  const float* W_fc = (const float*)d_in[20]; const float* b_fc = (const float*)d_in[21];

  // d_out layout (all f32): preds | caps | dec_len | alphas | order
  float* out_preds = (float*)d_out;
  float* out_caps  = out_preds + (size_t)NB*NT*NV;
  float* out_dlen  = out_caps + NB*NL;
  float* out_alph  = out_dlen + NB;
  float* out_order = out_alph + (size_t)NB*NT*NP;

  char* ws = (char*)d_ws;
  size_t off = 0;
  auto alloc = [&](size_t bytes)->size_t{ size_t r = off; off += (bytes + 255) & ~(size_t)255; return r; };
  bf16_t* enc_b   = (bf16_t*)(ws + alloc((size_t)12544*2048*2));
  char*   reg_att1 = ws + alloc((size_t)12544*512*2);       // att1_b; ipart overlaps (setup-only, pre-att1)
  bf16_t* att1_b  = (bf16_t*)reg_att1;
  float*  ipart   = (float*)reg_att1;
  char*   reg_h2   = ws + alloc((size_t)3328*512*2);        // h2all; Wea_b overlaps (setup-only)
  bf16_t* h2all_b = (bf16_t*)reg_h2;
  bf16_t* Wea_b   = (bf16_t*)reg_h2;
  bf16_t* Wdafb_b = (bf16_t*)(ws + alloc((size_t)2560*512*2));
  bf16_t* Wcat_b  = (bf16_t*)(ws + alloc((size_t)2048*3072*2));
  bf16_t* Wfc_b   = (bf16_t*)(ws + alloc((size_t)10000*512*2));
  char*   reg_wi  = ws + alloc((size_t)1024*2048*2);        // Winit (setup) / embAll (loop) overlap
  bf16_t* Winit_b = (bf16_t*)reg_wi;
  bf16_t* embAll  = (bf16_t*)reg_wi;                         // 51*64*512*2 = 3.34MB <= 4.19MB
  bf16_t* me_b    = (bf16_t*)(ws + alloc((size_t)64*2048*2));
  bf16_t* xh_awe  = (bf16_t*)(ws + alloc((size_t)64*2048*2));
  bf16_t* hbuf0   = (bf16_t*)(ws + alloc((size_t)64*512*2));
  bf16_t* hbuf1   = (bf16_t*)(ws + alloc((size_t)64*512*2));
  float*  c_f     = (float*)(ws + alloc((size_t)64*512*4));
  float*  a2gp_f  = (float*)(ws + alloc((size_t)4*64*2560*4));
  float*  e_f     = (float*)(ws + alloc((size_t)64*196*4));
  int*    order_i = (int*)(ws + alloc(64*4));
  int*    dlen_i  = (int*)(ws + alloc(64*4));
  int*    nact_i  = (int*)(ws + alloc(64*4));
  int*    caps_i  = (int*)(ws + alloc((size_t)64*52*4));
  int*    flags_i = (int*)(ws + alloc((size_t)(NT*64+64)*4));  // eflags[t][b] then gflags[t]

  k_sort<<<1,64,0,stream>>>(caption_lengths, encoded_captions, order_i, dlen_i, caps_i, nact_i,
                            flags_i, out_caps, out_dlen, out_order);
  k_cvt4<<<2048,256,0,stream>>>(encoder_out, enc_b, 12544*2048/4);
  k_cvt4<<<512,256,0,stream>>>(W_ea, Wea_b, 512*2048/4);
  k_cvt4<<<256,256,0,stream>>>(W_da, Wdafb_b, 512*512/4);
  k_cvt4<<<512,256,0,stream>>>(W_fb, Wdafb_b + 512*512, 2048*512/4);
  k_cvt2d4<<<1024,256,0,stream>>>(W_ih, 2048, 2560, Wcat_b, 3072, 0);
  k_cvt2d4<<<512,256,0,stream>>>(W_hh, 2048, 512, Wcat_b, 3072, 2560);
  k_cvt4<<<512,256,0,stream>>>(W_init_h, Winit_b, 512*2048/4);
  k_cvt4<<<512,256,0,stream>>>(W_init_c, Winit_b + 512*2048, 512*2048/4);
  k_cvt4<<<1024,256,0,stream>>>(W_fc, Wfc_b, 10000*512/4);
  k_mean<<<dim3(64,8),256,0,stream>>>(enc_b, order_i, me_b);
  k_gemm_part<512><<<dim3(4,4),256,0,stream>>>(me_b, 2048, Winit_b, 2048, ipart, 1024);
  k_init_fin<<<128,256,0,stream>>>(ipart, b_init_h, b_init_c, c_f, hbuf0);
  // embAll overwrites Winit region — after init GEMM consumed Winit
  k_emb<<<dim3(NB,NT),256,0,stream>>>(caps_i, emb_table, embAll);
  // att1: XCD-swizzled 1D grid 392
  k_big<0><<<392,256,0,stream>>>(enc_b, 2048, 2048, Wea_b, 512, b_ea, nullptr, att1_b, nullptr);
  // initial a2g partials from h0 (4-way K-split)
  k_gemm_part<128><<<dim3(10,4),256,0,stream>>>(hbuf0, 512, Wdafb_b, 512, a2gp_f, 2560);

  bf16_t* hb[2] = { hbuf0, hbuf1 };
  for(int t=0;t<NT;t++){
    bf16_t* hr = hb[t&1];
    bf16_t* hw = hb[(t&1)^1];
    k_att<<<dim3(64,8),256,0,stream>>>(att1_b, enc_b, a2gp_f, b_da, b_fb, w_fa, b_fa,
                                       order_i, nact_i, e_f, out_alph, xh_awe,
                                       flags_i + t*64, t);
    k_cell<<<168,256,0,stream>>>(embAll + (size_t)t*NB*512, xh_awe, hr, hw, Wcat_b,
                                 b_ih, b_hh, c_f, h2all_b, Wdafb_b, a2gp_f,
                                 dlen_i, flags_i + NT*64 + t, t);
  }
  // deferred preds GEMM: XCD-swizzled 1D grid 2054
  k_big<2><<<2054,256,0,stream>>>(h2all_b, 512, 512, Wfc_b, NV, b_fc, out_preds, nullptr, dlen_i);
}

// Round 13
// 2671.562 us; speedup vs baseline: 1.8610x; 1.8610x over previous
//
#include <hip/hip_runtime.h>
#include <cmath>

#define NB 64
#define NP 196
#define NE 2048
#define NV 10000
#define NL 52
#define NT 51

typedef unsigned short bf16_t;
typedef __attribute__((ext_vector_type(8))) short bf16x8;
typedef __attribute__((ext_vector_type(4))) float f32x4;

__device__ inline unsigned short f2bf(float f){
  unsigned int x = __float_as_uint(f);
  unsigned int r = x + 0x7fffu + ((x>>16)&1u);
  return (unsigned short)(r>>16);
}
__device__ inline float bf2f(unsigned short u){ return __uint_as_float(((unsigned int)u)<<16); }
__device__ inline float sigm(float x){ return 1.f/(1.f+expf(-x)); }

// ---------------- sort (stable descending by length) + nact ----------------
__global__ void k_sort(const int* __restrict__ cap_len, const int* __restrict__ caps,
                       int* __restrict__ order, int* __restrict__ dlen, int* __restrict__ caps_s,
                       int* __restrict__ nact,
                       float* __restrict__ out_caps, float* __restrict__ out_dlen, float* __restrict__ out_order){
  __shared__ int len_s[NB];
  __shared__ int ord_s[NB];
  __shared__ int dls[NB];
  int t = threadIdx.x; // 64 threads
  len_s[t] = cap_len[t];
  __syncthreads();
  int li = len_s[t]; int rank = 0;
  for(int j=0;j<NB;j++){ int lj = len_s[j]; rank += ((lj > li) || (lj==li && j<t)) ? 1 : 0; }
  ord_s[rank] = t;
  __syncthreads();
  int ob = ord_s[t];
  order[t] = ob; out_order[t] = (float)ob;
  int ls = len_s[ob]; dlen[t] = ls-1; out_dlen[t] = (float)(ls-1); dls[t] = ls-1;
  for(int l=0;l<NL;l++){ int cv = caps[ob*NL + l]; caps_s[t*NL+l]=cv; out_caps[t*NL+l] = (float)cv; }
  __syncthreads();
  if(t < NT){
    int cnt=0;
    for(int b=0;b<NB;b++) cnt += (dls[b] > t) ? 1 : 0;
    nact[t] = cnt;
  }
}

// ---------------- enc f32 -> bf16 ----------------
__global__ __launch_bounds__(256) void k_cvt4(const float* __restrict__ src, bf16_t* __restrict__ dst, int n4){
  int i = blockIdx.x*blockDim.x + threadIdx.x;
  int stride = gridDim.x*blockDim.x;
  for(; i<n4; i+=stride){
    float4 v = ((const float4*)src)[i];
    unsigned long long p = (unsigned long long)f2bf(v.x)
        | ((unsigned long long)f2bf(v.y)<<16)
        | ((unsigned long long)f2bf(v.z)<<32)
        | ((unsigned long long)f2bf(v.w)<<48);
    ((unsigned long long*)dst)[i] = p;
  }
}

// ---------------- all-weights converter: 8 regions in one dispatch ----------------
struct CvtRegs {
  const float* src[8];
  bf16_t* dst[8];
  int start[9];   // prefix offsets in f4 units
  int cols4[8];   // src row length / 4
  int dld[8];     // dst row stride (elements)
};

__global__ __launch_bounds__(256) void k_cvtw(CvtRegs R, int total4){
  int gid = blockIdx.x*blockDim.x + threadIdx.x;
  int stride = gridDim.x*blockDim.x;
  for(; gid<total4; gid+=stride){
    int rgn = 0;
    while(gid >= R.start[rgn+1]) rgn++;
    int i = gid - R.start[rgn];
    int c4n = R.cols4[rgn];
    int r = i / c4n, c4 = i - r*c4n;
    float4 v = ((const float4*)R.src[rgn])[i];
    unsigned long long p = (unsigned long long)f2bf(v.x)
        | ((unsigned long long)f2bf(v.y)<<16)
        | ((unsigned long long)f2bf(v.z)<<32)
        | ((unsigned long long)f2bf(v.w)<<48);
    *(unsigned long long*)(R.dst[rgn] + (size_t)r*R.dld[rgn] + c4*4) = p;
  }
}

// ---------------- mean over P from bf16 enc ----------------
__global__ __launch_bounds__(256) void k_mean(const bf16_t* __restrict__ encb, const int* __restrict__ order,
                                              bf16_t* __restrict__ me_s){
  int bs = blockIdx.x; int ec = blockIdx.y; int e = ec*256 + threadIdx.x;
  int ob = order[bs];
  const bf16_t* p = encb + (size_t)ob*NP*NE + e;
  float acc=0.f;
  for(int q=0;q<NP;q++) acc += bf2f(p[(size_t)q*NE]);
  me_s[(size_t)bs*NE + e] = f2bf(acc * (1.0f/NP));
}

// ---------------- embedding precompute: embAll[t][b][512] ----------------
__global__ __launch_bounds__(256) void k_emb(const int* __restrict__ caps_s, const float* __restrict__ emb_table,
                                             bf16_t* __restrict__ embAll){
  int b = blockIdx.x, t = blockIdx.y, tid = threadIdx.x;
  int cap = caps_s[b*NL + t];
  bf16_t* dst = embAll + ((size_t)t*NB + b)*512;
  const float* src = emb_table + (size_t)cap*512;
  dst[tid]       = f2bf(src[tid]);
  dst[tid + 256] = f2bf(src[tid + 256]);
}

// ---------------- big GEMM (128x128 tiles), XCD-swizzled 1D grid ----------------
// MODE0: att1 (bf16 out), grid 392. MODE2: preds (f32 out, masked, LDS-staged writes), grid 2054.
template<int MODE>
__global__ __launch_bounds__(256) void k_big(const bf16_t* __restrict__ A, int lda, int Kdim,
      const bf16_t* __restrict__ Bw, int nrowsB,
      const float* __restrict__ bias, float* __restrict__ outf, bf16_t* __restrict__ outb,
      const int* __restrict__ dlen){
  __shared__ __align__(16) char smem_raw[36864];
  bf16_t (*As)[72] = (bf16_t(*)[72])smem_raw;
  bf16_t (*Bs)[72] = (bf16_t(*)[72])(smem_raw + 18432);
  int lid = blockIdx.x;
  int nblk, mblk;
  if(MODE==0){
    int wg = (lid&7)*49 + (lid>>3);     // 392/8 = 49 exact
    mblk = wg>>2; nblk = wg&3;
  } else {
    int xcd = lid&7; int idx = lid>>3;  // 2054 = 8*256 + 6
    int wg = (xcd<6) ? xcd*257 + idx : 1542 + (xcd-6)*256 + idx;
    nblk = wg/26; mblk = wg - nblk*26;
  }
  int tid = threadIdx.x;
  int w = tid>>6, l = tid&63;
  int moff = (w>>1)*64, noff = (w&1)*64;
  f32x4 acc[4][4] = {};
  const int mbase = mblk*128, nbase = nblk*128;
  for(int k0=0; k0<Kdim; k0+=64){
    __syncthreads();
    for(int u=0;u<4;u++){
      int lin = u*256 + tid; int row = lin>>3; int col = (lin&7)*8;
      *(bf16x8*)(&As[row][col]) = *(const bf16x8*)(A + (size_t)(mbase+row)*lda + k0 + col);
      int rB = nbase+row; if(MODE==2 && rB >= nrowsB) rB = nrowsB-1;
      *(bf16x8*)(&Bs[row][col]) = *(const bf16x8*)(Bw + (size_t)rB*lda + k0 + col);
    }
    __syncthreads();
    for(int kk=0;kk<2;kk++){
      bf16x8 af[4], bfr[4];
      for(int m=0;m<4;m++) af[m] = *(bf16x8*)(&As[moff + 16*m + (l&15)][kk*32 + (l>>4)*8]);
      for(int n=0;n<4;n++) bfr[n] = *(bf16x8*)(&Bs[noff + 16*n + (l&15)][kk*32 + (l>>4)*8]);
      for(int m=0;m<4;m++)
        for(int n=0;n<4;n++)
          acc[m][n] = __builtin_amdgcn_mfma_f32_16x16x32_bf16(af[m], bfr[n], acc[m][n], 0,0,0);
    }
  }
  if(MODE==0){
    for(int m=0;m<4;m++) for(int n=0;n<4;n++){
      int col = nbase + noff + 16*n + (l&15);
      float bi = bias[col];
      for(int r=0;r<4;r++){
        int row = mbase + moff + 16*m + (l>>4)*4 + r;
        outb[(size_t)row*512 + col] = f2bf(acc[m][n][r] + bi);
      }
    }
  } else {
    float* st = (float*)smem_raw;  // 64*128*4 = 32768 <= 36864
    for(int h=0; h<2; ++h){
      __syncthreads();
      if((w>>1)==h){
        for(int m=0;m<4;m++) for(int n=0;n<4;n++)
          for(int r=0;r<4;r++)
            st[(16*m + (l>>4)*4 + r)*128 + noff + 16*n + (l&15)] = acc[m][n][r];
      }
      __syncthreads();
      for(int rr = tid>>5; rr<64; rr+=8){
        int row = mbase + h*64 + rr;
        if(row < NT*NB){
          int tt = row>>6, bb = row&63;
          int cc = (tid&31)*4;
          int col0 = nbase + cc;
          if(col0 < NV){
            float4 v = *(float4*)&st[rr*128 + cc];
            float4 bi4 = *(const float4*)&bias[col0];
            v.x+=bi4.x; v.y+=bi4.y; v.z+=bi4.z; v.w+=bi4.w;
            if(tt >= dlen[bb]){ v.x=0.f; v.y=0.f; v.z=0.f; v.w=0.f; }
            *(float4*)&outf[((size_t)bb*NT + tt)*NV + col0] = v;
          }
        }
      }
    }
  }
}

// ---------------- small-M (64) GEMM with K-split: partials ----------------
template<int KSL>
__global__ __launch_bounds__(256) void k_gemm_part(const bf16_t* __restrict__ Ax, int lda,
        const bf16_t* __restrict__ W, int ldw, float* __restrict__ part, int N){
  __shared__ bf16_t As[64][KSL+8];
  int ntile = blockIdx.x, ks = blockIdx.y;
  int tid = threadIdx.x; int w = tid>>6, l = tid&63;
  int k0 = ks*KSL;
  constexpr int UPR = KSL/8;
  constexpr int UPT = 64*UPR/256;
  for(int u=0;u<UPT;u++){
    int lin = u*256 + tid; int row = lin/UPR; int col = (lin%UPR)*8;
    *(bf16x8*)(&As[row][col]) = *(const bf16x8*)(Ax + (size_t)row*lda + k0 + col);
  }
  __syncthreads();
  f32x4 acc[4][4] = {};
  int nbase = ntile*256 + w*64;
  for(int kk=0; kk<KSL/32; kk++){
    bf16x8 af[4], bfr[4];
    for(int m=0;m<4;m++) af[m] = *(bf16x8*)(&As[16*m + (l&15)][kk*32 + (l>>4)*8]);
    for(int n=0;n<4;n++) bfr[n] = *(const bf16x8*)(W + (size_t)(nbase + 16*n + (l&15))*ldw + k0 + kk*32 + (l>>4)*8);
    for(int m=0;m<4;m++)
      for(int n=0;n<4;n++)
        acc[m][n] = __builtin_amdgcn_mfma_f32_16x16x32_bf16(af[m], bfr[n], acc[m][n], 0,0,0);
  }
  float* po = part + (size_t)ks*64*N;
  for(int m=0;m<4;m++) for(int n=0;n<4;n++){
    int col = nbase + 16*n + (l&15);
    for(int r=0;r<4;r++){
      int row = 16*m + (l>>4)*4 + r;
      po[(size_t)row*N + col] = acc[m][n][r];
    }
  }
}

// ---------------- combine init partials -> h0 (hbuf0), c0 ----------------
__global__ __launch_bounds__(256) void k_init_fin(const float* __restrict__ part,
        const float* __restrict__ b_ih_, const float* __restrict__ b_ic_,
        float* __restrict__ c, bf16_t* __restrict__ h0){
  int idx = blockIdx.x*256 + threadIdx.x;  // 0..32767
  int b_ = idx>>9, d = idx&511;
  float h = b_ih_[d], cc = b_ic_[d];
  for(int ks=0;ks<4;ks++){
    const float* p = part + (size_t)ks*64*1024 + (size_t)b_*1024;
    h += p[d]; cc += p[512+d];
  }
  c[idx] = cc;
  h0[(size_t)b_*512 + d] = f2bf(h);
}

// ---------------- e-scores: grid (64 b, 4 p-groups) x 256 ----------------
__global__ __launch_bounds__(256) void k_e(const bf16_t* __restrict__ att1,
    const float* __restrict__ a2g, const float* __restrict__ b_da,
    const float* __restrict__ w_fa, const float* __restrict__ b_fa,
    const int* __restrict__ order, const int* __restrict__ nact,
    float* __restrict__ e_out, int t){
  int b_ = blockIdx.x, pg = blockIdx.y, tid = threadIdx.x;
  if(b_ >= nact[t]) return;
  int w = tid>>6, l = tid&63;
  int ob = order[b_];
  const float* pa0 = a2g + ((size_t)0*NB + b_)*2560;
  const float* pa1 = a2g + ((size_t)1*NB + b_)*2560;
  const float* pa2 = a2g + ((size_t)2*NB + b_)*2560;
  const float* pa3 = a2g + ((size_t)3*NB + b_)*2560;
  float ar[8], wr[8];
  #pragma unroll
  for(int q=0;q<8;q++){
    int i = l*8 + q;
    ar[q] = pa0[i] + pa1[i] + pa2[i] + pa3[i] + b_da[i];
    wr[q] = w_fa[i];
  }
  float bfa0 = b_fa[0];
  for(int pl=w; pl<49; pl+=4){
    int p = pg*49 + pl;
    bf16x8 a1v = *(const bf16x8*)(att1 + ((size_t)ob*NP + p)*512 + l*8);
    float s = 0.f;
    #pragma unroll
    for(int q=0;q<8;q++){
      float v = bf2f((unsigned short)a1v[q]) + ar[q];
      v = v>0.f ? v : 0.f;
      s += v*wr[q];
    }
    #pragma unroll
    for(int off=32;off;off>>=1) s += __shfl_down(s, off);
    if(l==0) e_out[b_*NP + p] = s + bfa0;
  }
}

// ---------------- softmax (redundant/block) + awe + gate: grid (64 b, 4 col-slices) x 256 ----------------
__global__ __launch_bounds__(256) void k_awe(const bf16_t* __restrict__ enc, const float* __restrict__ e_in,
    const float* __restrict__ a2g, const float* __restrict__ b_fb,
    const int* __restrict__ order, const int* __restrict__ nact,
    float* __restrict__ alphas_out, bf16_t* __restrict__ xh_awe, int t){
  int b_ = blockIdx.x, y = blockIdx.y, tid = threadIdx.x;
  if(b_ >= nact[t]){
    if(y==0 && tid<NP) alphas_out[((size_t)b_*NT + t)*NP + tid] = 0.f;
    return;
  }
  __shared__ float al[200];
  __shared__ float red[8];
  __shared__ float aw[4][512];
  int w = tid>>6, l = tid&63;
  // softmax over 196 with 4 waves
  float v = (tid<NP)? e_in[b_*NP + tid] : -1e30f;
  float m = v;
  #pragma unroll
  for(int off=32;off;off>>=1) m = fmaxf(m, __shfl_down(m, off));
  if(l==0) red[w] = m;
  __syncthreads();
  float mx = fmaxf(fmaxf(red[0],red[1]), fmaxf(red[2],red[3]));
  float ex = (tid<NP)? expf(v - mx) : 0.f;
  float s2 = ex;
  #pragma unroll
  for(int off=32;off;off>>=1) s2 += __shfl_down(s2, off);
  if(l==0) red[4+w] = s2;
  __syncthreads();
  float inv = 1.f/(red[4]+red[5]+red[6]+red[7]);
  if(tid<NP){
    float a = ex*inv;
    al[tid] = a;
    if(y==0) alphas_out[((size_t)b_*NT + t)*NP + tid] = a;
  }
  __syncthreads();
  // awe for cols [y*512, y*512+512): wave w handles p-rows [w*49, w*49+49), lane covers 8 cols
  int ob = order[b_];
  int j0 = y*512 + l*8;
  float a8[8] = {};
  const bf16_t* ep = enc + (size_t)ob*NP*NE + j0;
  int p0 = w*49;
  #pragma unroll 4
  for(int pp=0; pp<49; ++pp){
    int p = p0 + pp;
    bf16x8 ev = *(const bf16x8*)(ep + (size_t)p*NE);
    float alp = al[p];
    #pragma unroll
    for(int q=0;q<8;q++) a8[q] += alp*bf2f((unsigned short)ev[q]);
  }
  #pragma unroll
  for(int q=0;q<8;q++) aw[w][l*8 + q] = a8[q];
  __syncthreads();
  // combine 4 p-partials + gate, write bf16 (2 cols/thread)
  const float* pa0 = a2g + ((size_t)0*NB + b_)*2560;
  const float* pa1 = a2g + ((size_t)1*NB + b_)*2560;
  const float* pa2 = a2g + ((size_t)2*NB + b_)*2560;
  const float* pa3 = a2g + ((size_t)3*NB + b_)*2560;
  int jl = tid*2;
  int j  = y*512 + jl;
  #pragma unroll
  for(int q=0;q<2;q++){
    float s = aw[0][jl+q] + aw[1][jl+q] + aw[2][jl+q] + aw[3][jl+q];
    int jj = 512 + j + q;
    float gpre = pa0[jj] + pa1[jj] + pa2[jj] + pa3[jj] + b_fb[j + q];
    xh_awe[(size_t)b_*2048 + j + q] = f2bf(sigm(gpre)*s);
  }
}

// ---------------- fused gates GEMM + LSTM cell: 128 blocks ----------------
// block j owns 16 output cols {g*512 + j*4 + c : g<4, c<4}; K=3072 split across 4 waves
__global__ __launch_bounds__(256) void k_gatecell(const bf16_t* __restrict__ embT,
    const bf16_t* __restrict__ xh_awe, const bf16_t* __restrict__ hr,
    bf16_t* __restrict__ hw, const bf16_t* __restrict__ Wcat,
    const float* __restrict__ b_ih, const float* __restrict__ b_hh,
    float* __restrict__ cbuf, bf16_t* __restrict__ h2all,
    const int* __restrict__ dlen, int t){
  __shared__ float part[4][64][16];
  int j = blockIdx.x, tid = threadIdx.x;
  int w = tid>>6, l = tid&63;
  int n_ = l&15;
  int wrow = (n_>>2)*512 + j*4 + (n_&3);
  const bf16_t* wp = Wcat + (size_t)wrow*3072;
  f32x4 acc[4] = {};
  int k0w = w*768;
  for(int kk=0;kk<24;kk++){
    int col = k0w + kk*32 + (l>>4)*8;
    bf16x8 af[4], bg;
    if(col < 512){
      #pragma unroll
      for(int m=0;m<4;m++) af[m] = *(const bf16x8*)(embT + (size_t)(16*m + n_)*512 + col);
    } else if(col < 2560){
      #pragma unroll
      for(int m=0;m<4;m++) af[m] = *(const bf16x8*)(xh_awe + (size_t)(16*m + n_)*2048 + col - 512);
    } else {
      #pragma unroll
      for(int m=0;m<4;m++) af[m] = *(const bf16x8*)(hr + (size_t)(16*m + n_)*512 + col - 2560);
    }
    bg = *(const bf16x8*)(wp + col);
    #pragma unroll
    for(int m=0;m<4;m++)
      acc[m] = __builtin_amdgcn_mfma_f32_16x16x32_bf16(af[m], bg, acc[m], 0,0,0);
  }
  #pragma unroll
  for(int m=0;m<4;m++)
    #pragma unroll
    for(int r=0;r<4;r++)
      part[w][16*m + (l>>4)*4 + r][n_] = acc[m][r];
  __syncthreads();
  // cell: one output per thread (64 b x 4 c)
  int b = tid>>2, c = tid&3;
  int dg = j*4 + c;
  float gs[4];
  #pragma unroll
  for(int g=0;g<4;g++){
    gs[g] = b_ih[g*512+dg] + b_hh[g*512+dg]
          + part[0][b][g*4+c] + part[1][b][g*4+c]
          + part[2][b][g*4+c] + part[3][b][g*4+c];
  }
  float oldc = cbuf[b*512 + dg];
  float c2 = sigm(gs[1])*oldc + sigm(gs[0])*tanhf(gs[2]);
  float h2 = sigm(gs[3])*tanhf(c2);
  bool mk = t < dlen[b];
  if(mk) cbuf[b*512 + dg] = c2;
  hw[(size_t)b*512 + dg] = mk ? f2bf(h2) : hr[(size_t)b*512 + dg];
  h2all[((size_t)t*NB + b)*512 + dg] = f2bf(h2);
}

// ---------------- launcher ----------------
extern "C" void kernel_launch(void* const* d_in, const int* in_sizes, int n_in,
                              void* d_out, int out_size, void* d_ws, size_t ws_size,
                              hipStream_t stream){
  (void)in_sizes; (void)n_in; (void)out_size; (void)ws_size;
  const float* encoder_out      = (const float*)d_in[0];
  const int*   encoded_captions = (const int*)d_in[1];
  const int*   caption_lengths  = (const int*)d_in[2];
  const float* W_ea = (const float*)d_in[3];  const float* b_ea = (const float*)d_in[4];
  const float* W_da = (const float*)d_in[5];  const float* b_da = (const float*)d_in[6];
  const float* w_fa = (const float*)d_in[7];  const float* b_fa = (const float*)d_in[8];
  const float* emb_table = (const float*)d_in[9];
  const float* W_ih = (const float*)d_in[10]; const float* b_ih = (const float*)d_in[11];
  const float* W_hh = (const float*)d_in[12]; const float* b_hh = (const float*)d_in[13];
  const float* W_init_h = (const float*)d_in[14]; const float* b_init_h = (const float*)d_in[15];
  const float* W_init_c = (const float*)d_in[16]; const float* b_init_c = (const float*)d_in[17];
  const float* W_fb = (const float*)d_in[18]; const float* b_fb = (const float*)d_in[19];
  const float* W_fc = (const float*)d_in[20]; const float* b_fc = (const float*)d_in[21];

  // d_out layout (all f32): preds | caps | dec_len | alphas | order
  float* out_preds = (float*)d_out;
  float* out_caps  = out_preds + (size_t)NB*NT*NV;
  float* out_dlen  = out_caps + NB*NL;
  float* out_alph  = out_dlen + NB;
  float* out_order = out_alph + (size_t)NB*NT*NP;

  char* ws = (char*)d_ws;
  size_t off = 0;
  auto alloc = [&](size_t bytes)->size_t{ size_t r = off; off += (bytes + 255) & ~(size_t)255; return r; };
  bf16_t* enc_b   = (bf16_t*)(ws + alloc((size_t)12544*2048*2));
  char*   reg_att1 = ws + alloc((size_t)12544*512*2);       // att1_b; ipart overlaps (setup-only, pre-att1)
  bf16_t* att1_b  = (bf16_t*)reg_att1;
  float*  ipart   = (float*)reg_att1;
  char*   reg_h2   = ws + alloc((size_t)3328*512*2);        // h2all; Wea_b overlaps (setup-only)
  bf16_t* h2all_b = (bf16_t*)reg_h2;
  bf16_t* Wea_b   = (bf16_t*)reg_h2;
  bf16_t* Wdafb_b = (bf16_t*)(ws + alloc((size_t)2560*512*2));
  bf16_t* Wcat_b  = (bf16_t*)(ws + alloc((size_t)2048*3072*2));
  bf16_t* Wfc_b   = (bf16_t*)(ws + alloc((size_t)10000*512*2));
  char*   reg_wi  = ws + alloc((size_t)1024*2048*2);        // Winit (setup) / embAll (loop) overlap
  bf16_t* Winit_b = (bf16_t*)reg_wi;
  bf16_t* embAll  = (bf16_t*)reg_wi;                         // 51*64*512*2 = 3.34MB <= 4.19MB
  bf16_t* me_b    = (bf16_t*)(ws + alloc((size_t)64*2048*2));
  bf16_t* xh_awe  = (bf16_t*)(ws + alloc((size_t)64*2048*2));
  bf16_t* hbuf0   = (bf16_t*)(ws + alloc((size_t)64*512*2));
  bf16_t* hbuf1   = (bf16_t*)(ws + alloc((size_t)64*512*2));
  float*  c_f     = (float*)(ws + alloc((size_t)64*512*4));
  float*  a2gp_f  = (float*)(ws + alloc((size_t)4*64*2560*4));
  float*  e_f     = (float*)(ws + alloc((size_t)64*196*4));
  int*    order_i = (int*)(ws + alloc(64*4));
  int*    dlen_i  = (int*)(ws + alloc(64*4));
  int*    nact_i  = (int*)(ws + alloc(64*4));
  int*    caps_i  = (int*)(ws + alloc((size_t)64*52*4));

  k_sort<<<1,64,0,stream>>>(caption_lengths, encoded_captions, order_i, dlen_i, caps_i, nact_i,
                            out_caps, out_dlen, out_order);
  k_cvt4<<<2048,256,0,stream>>>(encoder_out, enc_b, 12544*2048/4);

  // merged weight conversions: 8 regions, one dispatch
  CvtRegs R;
  int n4s[8];
  R.src[0] = W_ea;      R.dst[0] = Wea_b;               n4s[0] = 512*2048/4;  R.cols4[0] = 512; R.dld[0] = 2048;
  R.src[1] = W_da;      R.dst[1] = Wdafb_b;             n4s[1] = 512*512/4;   R.cols4[1] = 128; R.dld[1] = 512;
  R.src[2] = W_fb;      R.dst[2] = Wdafb_b + 512*512;   n4s[2] = 2048*512/4;  R.cols4[2] = 128; R.dld[2] = 512;
  R.src[3] = W_ih;      R.dst[3] = Wcat_b;              n4s[3] = 2048*2560/4; R.cols4[3] = 640; R.dld[3] = 3072;
  R.src[4] = W_hh;      R.dst[4] = Wcat_b + 2560;       n4s[4] = 2048*512/4;  R.cols4[4] = 128; R.dld[4] = 3072;
  R.src[5] = W_init_h;  R.dst[5] = Winit_b;             n4s[5] = 512*2048/4;  R.cols4[5] = 512; R.dld[5] = 2048;
  R.src[6] = W_init_c;  R.dst[6] = Winit_b + 512*2048;  n4s[6] = 512*2048/4;  R.cols4[6] = 512; R.dld[6] = 2048;
  R.src[7] = W_fc;      R.dst[7] = Wfc_b;               n4s[7] = 10000*512/4; R.cols4[7] = 128; R.dld[7] = 512;
  R.start[0] = 0;
  for(int i=0;i<8;i++) R.start[i+1] = R.start[i] + n4s[i];
  k_cvtw<<<1024,256,0,stream>>>(R, R.start[8]);

  k_mean<<<dim3(64,8),256,0,stream>>>(enc_b, order_i, me_b);
  k_gemm_part<512><<<dim3(4,4),256,0,stream>>>(me_b, 2048, Winit_b, 2048, ipart, 1024);
  k_init_fin<<<128,256,0,stream>>>(ipart, b_init_h, b_init_c, c_f, hbuf0);
  // embAll overwrites Winit region — after init GEMM consumed Winit
  k_emb<<<dim3(NB,NT),256,0,stream>>>(caps_i, emb_table, embAll);
  // att1: XCD-swizzled 1D grid 392
  k_big<0><<<392,256,0,stream>>>(enc_b, 2048, 2048, Wea_b, 512, b_ea, nullptr, att1_b, nullptr);
  // initial a2g partials from h0 (4-way K-split)
  k_gemm_part<128><<<dim3(10,4),256,0,stream>>>(hbuf0, 512, Wdafb_b, 512, a2gp_f, 2560);

  bf16_t* hb[2] = { hbuf0, hbuf1 };
  for(int t=0;t<NT;t++){
    bf16_t* hr = hb[t&1];
    bf16_t* hw = hb[(t&1)^1];
    k_e<<<dim3(64,4),256,0,stream>>>(att1_b, a2gp_f, b_da, w_fa, b_fa, order_i, nact_i, e_f, t);
    k_awe<<<dim3(64,4),256,0,stream>>>(enc_b, e_f, a2gp_f, b_fb, order_i, nact_i,
                                       out_alph, xh_awe, t);
    k_gatecell<<<128,256,0,stream>>>(embAll + (size_t)t*NB*512, xh_awe, hr, hw, Wcat_b,
                                     b_ih, b_hh, c_f, h2all_b, dlen_i, t);
    k_gemm_part<128><<<dim3(10,4),256,0,stream>>>(hw, 512, Wdafb_b, 512, a2gp_f, 2560);
  }
  // deferred preds GEMM: XCD-swizzled 1D grid 2054
  k_big<2><<<2054,256,0,stream>>>(h2all_b, 512, 512, Wfc_b, NV, b_fc, out_preds, nullptr, dlen_i);
}

// Round 14
// 2514.021 us; speedup vs baseline: 1.9776x; 1.0627x over previous
//
#include <hip/hip_runtime.h>
#include <cmath>

#define NB 64
#define NP 196
#define NE 2048
#define NV 10000
#define NL 52
#define NT 51

typedef unsigned short bf16_t;
typedef __attribute__((ext_vector_type(8))) short bf16x8;
typedef __attribute__((ext_vector_type(4))) float f32x4;

__device__ inline unsigned short f2bf(float f){
  unsigned int x = __float_as_uint(f);
  unsigned int r = x + 0x7fffu + ((x>>16)&1u);
  return (unsigned short)(r>>16);
}
__device__ inline float bf2f(unsigned short u){ return __uint_as_float(((unsigned int)u)<<16); }
__device__ inline float sigm(float x){ return 1.f/(1.f+expf(-x)); }

// ---------------- sort (stable descending by length) + nact ----------------
__global__ void k_sort(const int* __restrict__ cap_len, const int* __restrict__ caps,
                       int* __restrict__ order, int* __restrict__ dlen, int* __restrict__ caps_s,
                       int* __restrict__ nact,
                       float* __restrict__ out_caps, float* __restrict__ out_dlen, float* __restrict__ out_order){
  __shared__ int len_s[NB];
  __shared__ int ord_s[NB];
  __shared__ int dls[NB];
  int t = threadIdx.x; // 64 threads
  len_s[t] = cap_len[t];
  __syncthreads();
  int li = len_s[t]; int rank = 0;
  for(int j=0;j<NB;j++){ int lj = len_s[j]; rank += ((lj > li) || (lj==li && j<t)) ? 1 : 0; }
  ord_s[rank] = t;
  __syncthreads();
  int ob = ord_s[t];
  order[t] = ob; out_order[t] = (float)ob;
  int ls = len_s[ob]; dlen[t] = ls-1; out_dlen[t] = (float)(ls-1); dls[t] = ls-1;
  for(int l=0;l<NL;l++){ int cv = caps[ob*NL + l]; caps_s[t*NL+l]=cv; out_caps[t*NL+l] = (float)cv; }
  __syncthreads();
  if(t < NT){
    int cnt=0;
    for(int b=0;b<NB;b++) cnt += (dls[b] > t) ? 1 : 0;
    nact[t] = cnt;
  }
}

// ---------------- enc f32 -> bf16 ----------------
__global__ __launch_bounds__(256) void k_cvt4(const float* __restrict__ src, bf16_t* __restrict__ dst, int n4){
  int i = blockIdx.x*blockDim.x + threadIdx.x;
  int stride = gridDim.x*blockDim.x;
  for(; i<n4; i+=stride){
    float4 v = ((const float4*)src)[i];
    unsigned long long p = (unsigned long long)f2bf(v.x)
        | ((unsigned long long)f2bf(v.y)<<16)
        | ((unsigned long long)f2bf(v.z)<<32)
        | ((unsigned long long)f2bf(v.w)<<48);
    ((unsigned long long*)dst)[i] = p;
  }
}

// ---------------- all-weights converter: 8 regions in one dispatch ----------------
struct CvtRegs {
  const float* src[8];
  bf16_t* dst[8];
  int start[9];   // prefix offsets in f4 units
  int cols4[8];   // src row length / 4
  int dld[8];     // dst row stride (elements)
};

__global__ __launch_bounds__(256) void k_cvtw(CvtRegs R, int total4){
  int gid = blockIdx.x*blockDim.x + threadIdx.x;
  int stride = gridDim.x*blockDim.x;
  for(; gid<total4; gid+=stride){
    int rgn = 0;
    while(gid >= R.start[rgn+1]) rgn++;
    int i = gid - R.start[rgn];
    int c4n = R.cols4[rgn];
    int r = i / c4n, c4 = i - r*c4n;
    float4 v = ((const float4*)R.src[rgn])[i];
    unsigned long long p = (unsigned long long)f2bf(v.x)
        | ((unsigned long long)f2bf(v.y)<<16)
        | ((unsigned long long)f2bf(v.z)<<32)
        | ((unsigned long long)f2bf(v.w)<<48);
    *(unsigned long long*)(R.dst[rgn] + (size_t)r*R.dld[rgn] + c4*4) = p;
  }
}

// ---------------- mean over P from bf16 enc ----------------
__global__ __launch_bounds__(256) void k_mean(const bf16_t* __restrict__ encb, const int* __restrict__ order,
                                              bf16_t* __restrict__ me_s){
  int bs = blockIdx.x; int ec = blockIdx.y; int e = ec*256 + threadIdx.x;
  int ob = order[bs];
  const bf16_t* p = encb + (size_t)ob*NP*NE + e;
  float acc=0.f;
  for(int q=0;q<NP;q++) acc += bf2f(p[(size_t)q*NE]);
  me_s[(size_t)bs*NE + e] = f2bf(acc * (1.0f/NP));
}

// ---------------- embedding precompute: embAll[t][b][512] ----------------
__global__ __launch_bounds__(256) void k_emb(const int* __restrict__ caps_s, const float* __restrict__ emb_table,
                                             bf16_t* __restrict__ embAll){
  int b = blockIdx.x, t = blockIdx.y, tid = threadIdx.x;
  int cap = caps_s[b*NL + t];
  bf16_t* dst = embAll + ((size_t)t*NB + b)*512;
  const float* src = emb_table + (size_t)cap*512;
  dst[tid]       = f2bf(src[tid]);
  dst[tid + 256] = f2bf(src[tid + 256]);
}

// ---------------- big GEMM (128x128 tiles), XCD-swizzled 1D grid ----------------
// MODE0: att1 (bf16 out), grid 392. MODE2: preds (f32 out, masked, LDS-staged writes), grid 2054.
template<int MODE>
__global__ __launch_bounds__(256) void k_big(const bf16_t* __restrict__ A, int lda, int Kdim,
      const bf16_t* __restrict__ Bw, int nrowsB,
      const float* __restrict__ bias, float* __restrict__ outf, bf16_t* __restrict__ outb,
      const int* __restrict__ dlen){
  __shared__ __align__(16) char smem_raw[36864];
  bf16_t (*As)[72] = (bf16_t(*)[72])smem_raw;
  bf16_t (*Bs)[72] = (bf16_t(*)[72])(smem_raw + 18432);
  int lid = blockIdx.x;
  int nblk, mblk;
  if(MODE==0){
    int wg = (lid&7)*49 + (lid>>3);     // 392/8 = 49 exact
    mblk = wg>>2; nblk = wg&3;
  } else {
    int xcd = lid&7; int idx = lid>>3;  // 2054 = 8*256 + 6
    int wg = (xcd<6) ? xcd*257 + idx : 1542 + (xcd-6)*256 + idx;
    nblk = wg/26; mblk = wg - nblk*26;
  }
  int tid = threadIdx.x;
  int w = tid>>6, l = tid&63;
  int moff = (w>>1)*64, noff = (w&1)*64;
  f32x4 acc[4][4] = {};
  const int mbase = mblk*128, nbase = nblk*128;
  for(int k0=0; k0<Kdim; k0+=64){
    __syncthreads();
    for(int u=0;u<4;u++){
      int lin = u*256 + tid; int row = lin>>3; int col = (lin&7)*8;
      *(bf16x8*)(&As[row][col]) = *(const bf16x8*)(A + (size_t)(mbase+row)*lda + k0 + col);
      int rB = nbase+row; if(MODE==2 && rB >= nrowsB) rB = nrowsB-1;
      *(bf16x8*)(&Bs[row][col]) = *(const bf16x8*)(Bw + (size_t)rB*lda + k0 + col);
    }
    __syncthreads();
    for(int kk=0;kk<2;kk++){
      bf16x8 af[4], bfr[4];
      for(int m=0;m<4;m++) af[m] = *(bf16x8*)(&As[moff + 16*m + (l&15)][kk*32 + (l>>4)*8]);
      for(int n=0;n<4;n++) bfr[n] = *(bf16x8*)(&Bs[noff + 16*n + (l&15)][kk*32 + (l>>4)*8]);
      for(int m=0;m<4;m++)
        for(int n=0;n<4;n++)
          acc[m][n] = __builtin_amdgcn_mfma_f32_16x16x32_bf16(af[m], bfr[n], acc[m][n], 0,0,0);
    }
  }
  if(MODE==0){
    for(int m=0;m<4;m++) for(int n=0;n<4;n++){
      int col = nbase + noff + 16*n + (l&15);
      float bi = bias[col];
      for(int r=0;r<4;r++){
        int row = mbase + moff + 16*m + (l>>4)*4 + r;
        outb[(size_t)row*512 + col] = f2bf(acc[m][n][r] + bi);
      }
    }
  } else {
    float* st = (float*)smem_raw;  // 64*128*4 = 32768 <= 36864
    for(int h=0; h<2; ++h){
      __syncthreads();
      if((w>>1)==h){
        for(int m=0;m<4;m++) for(int n=0;n<4;n++)
          for(int r=0;r<4;r++)
            st[(16*m + (l>>4)*4 + r)*128 + noff + 16*n + (l&15)] = acc[m][n][r];
      }
      __syncthreads();
      for(int rr = tid>>5; rr<64; rr+=8){
        int row = mbase + h*64 + rr;
        if(row < NT*NB){
          int tt = row>>6, bb = row&63;
          int cc = (tid&31)*4;
          int col0 = nbase + cc;
          if(col0 < NV){
            float4 v = *(float4*)&st[rr*128 + cc];
            float4 bi4 = *(const float4*)&bias[col0];
            v.x+=bi4.x; v.y+=bi4.y; v.z+=bi4.z; v.w+=bi4.w;
            if(tt >= dlen[bb]){ v.x=0.f; v.y=0.f; v.z=0.f; v.w=0.f; }
            *(float4*)&outf[((size_t)bb*NT + tt)*NV + col0] = v;
          }
        }
      }
    }
  }
}

// ---------------- small-M (64) GEMM with K-split: partials ----------------
template<int KSL>
__global__ __launch_bounds__(256) void k_gemm_part(const bf16_t* __restrict__ Ax, int lda,
        const bf16_t* __restrict__ W, int ldw, float* __restrict__ part, int N){
  __shared__ bf16_t As[64][KSL+8];
  int ntile = blockIdx.x, ks = blockIdx.y;
  int tid = threadIdx.x; int w = tid>>6, l = tid&63;
  int k0 = ks*KSL;
  constexpr int UPR = KSL/8;
  constexpr int UPT = 64*UPR/256;
  for(int u=0;u<UPT;u++){
    int lin = u*256 + tid; int row = lin/UPR; int col = (lin%UPR)*8;
    *(bf16x8*)(&As[row][col]) = *(const bf16x8*)(Ax + (size_t)row*lda + k0 + col);
  }
  __syncthreads();
  f32x4 acc[4][4] = {};
  int nbase = ntile*256 + w*64;
  for(int kk=0; kk<KSL/32; kk++){
    bf16x8 af[4], bfr[4];
    for(int m=0;m<4;m++) af[m] = *(bf16x8*)(&As[16*m + (l&15)][kk*32 + (l>>4)*8]);
    for(int n=0;n<4;n++) bfr[n] = *(const bf16x8*)(W + (size_t)(nbase + 16*n + (l&15))*ldw + k0 + kk*32 + (l>>4)*8);
    for(int m=0;m<4;m++)
      for(int n=0;n<4;n++)
        acc[m][n] = __builtin_amdgcn_mfma_f32_16x16x32_bf16(af[m], bfr[n], acc[m][n], 0,0,0);
  }
  float* po = part + (size_t)ks*64*N;
  for(int m=0;m<4;m++) for(int n=0;n<4;n++){
    int col = nbase + 16*n + (l&15);
    for(int r=0;r<4;r++){
      int row = 16*m + (l>>4)*4 + r;
      po[(size_t)row*N + col] = acc[m][n][r];
    }
  }
}

// ---------------- combine init partials -> h0 (hbuf0), c0 ----------------
__global__ __launch_bounds__(256) void k_init_fin(const float* __restrict__ part,
        const float* __restrict__ b_ih_, const float* __restrict__ b_ic_,
        float* __restrict__ c, bf16_t* __restrict__ h0){
  int idx = blockIdx.x*256 + threadIdx.x;  // 0..32767
  int b_ = idx>>9, d = idx&511;
  float h = b_ih_[d], cc = b_ic_[d];
  for(int ks=0;ks<4;ks++){
    const float* p = part + (size_t)ks*64*1024 + (size_t)b_*1024;
    h += p[d]; cc += p[512+d];
  }
  c[idx] = cc;
  h0[(size_t)b_*512 + d] = f2bf(h);
}

// ---------------- e-scores: grid (64 b, 4 p-groups) x 256 ----------------
__global__ __launch_bounds__(256) void k_e(const bf16_t* __restrict__ att1,
    const float* __restrict__ a2g, const float* __restrict__ b_da,
    const float* __restrict__ w_fa, const float* __restrict__ b_fa,
    const int* __restrict__ order, const int* __restrict__ nact,
    float* __restrict__ e_out, int t){
  int b_ = blockIdx.x, pg = blockIdx.y, tid = threadIdx.x;
  if(b_ >= nact[t]) return;
  int w = tid>>6, l = tid&63;
  int ob = order[b_];
  const float* pa0 = a2g + ((size_t)0*NB + b_)*2560;
  const float* pa1 = a2g + ((size_t)1*NB + b_)*2560;
  const float* pa2 = a2g + ((size_t)2*NB + b_)*2560;
  const float* pa3 = a2g + ((size_t)3*NB + b_)*2560;
  float ar[8], wr[8];
  #pragma unroll
  for(int q=0;q<8;q++){
    int i = l*8 + q;
    ar[q] = pa0[i] + pa1[i] + pa2[i] + pa3[i] + b_da[i];
    wr[q] = w_fa[i];
  }
  float bfa0 = b_fa[0];
  for(int pl=w; pl<49; pl+=4){
    int p = pg*49 + pl;
    bf16x8 a1v = *(const bf16x8*)(att1 + ((size_t)ob*NP + p)*512 + l*8);
    float s = 0.f;
    #pragma unroll
    for(int q=0;q<8;q++){
      float v = bf2f((unsigned short)a1v[q]) + ar[q];
      v = v>0.f ? v : 0.f;
      s += v*wr[q];
    }
    #pragma unroll
    for(int off=32;off;off>>=1) s += __shfl_down(s, off);
    if(l==0) e_out[b_*NP + p] = s + bfa0;
  }
}

// ---------------- softmax (8-wave) + awe (8-wave p-split) + gate: grid (64 b, 4 col-slices) x 512 ----------------
__global__ __launch_bounds__(512) void k_awe(const bf16_t* __restrict__ enc, const float* __restrict__ e_in,
    const float* __restrict__ a2g, const float* __restrict__ b_fb,
    const int* __restrict__ order, const int* __restrict__ nact,
    float* __restrict__ alphas_out, bf16_t* __restrict__ xh_awe, int t){
  int b_ = blockIdx.x, y = blockIdx.y, tid = threadIdx.x;
  if(b_ >= nact[t]){
    if(y==0 && tid<NP) alphas_out[((size_t)b_*NT + t)*NP + tid] = 0.f;
    return;
  }
  __shared__ float al[200];
  __shared__ float red[16];
  __shared__ float aw[8][512];
  int w = tid>>6, l = tid&63;
  // softmax over 196 with 8 waves (waves 4-7 carry -inf/0)
  float v = (tid<NP)? e_in[b_*NP + tid] : -1e30f;
  float m = v;
  #pragma unroll
  for(int off=32;off;off>>=1) m = fmaxf(m, __shfl_down(m, off));
  if(l==0) red[w] = m;
  __syncthreads();
  float mx = red[0];
  #pragma unroll
  for(int i=1;i<8;i++) mx = fmaxf(mx, red[i]);
  float ex = (tid<NP)? expf(v - mx) : 0.f;
  float s2 = ex;
  #pragma unroll
  for(int off=32;off;off>>=1) s2 += __shfl_down(s2, off);
  if(l==0) red[8+w] = s2;
  __syncthreads();
  float sum = red[8];
  #pragma unroll
  for(int i=9;i<16;i++) sum += red[i];
  float inv = 1.f/sum;
  if(tid<NP){
    float a = ex*inv;
    al[tid] = a;
    if(y==0) alphas_out[((size_t)b_*NT + t)*NP + tid] = a;
  }
  __syncthreads();
  // awe for cols [y*512, y*512+512): wave w takes strided p (25 iters max), lane covers 8 cols
  int ob = order[b_];
  int j0 = y*512 + l*8;
  float a8[8] = {};
  const bf16_t* ep = enc + (size_t)ob*NP*NE + j0;
  for(int p=w; p<NP; p+=8){
    bf16x8 ev = *(const bf16x8*)(ep + (size_t)p*NE);
    float alp = al[p];
    #pragma unroll
    for(int q=0;q<8;q++) a8[q] += alp*bf2f((unsigned short)ev[q]);
  }
  #pragma unroll
  for(int q=0;q<8;q++) aw[w][l*8 + q] = a8[q];
  __syncthreads();
  // combine 8 p-partials + gate, write bf16 (1 col/thread)
  const float* pa0 = a2g + ((size_t)0*NB + b_)*2560;
  const float* pa1 = a2g + ((size_t)1*NB + b_)*2560;
  const float* pa2 = a2g + ((size_t)2*NB + b_)*2560;
  const float* pa3 = a2g + ((size_t)3*NB + b_)*2560;
  int jl = tid;   // 0..511
  float s = aw[0][jl] + aw[1][jl] + aw[2][jl] + aw[3][jl]
          + aw[4][jl] + aw[5][jl] + aw[6][jl] + aw[7][jl];
  int j  = y*512 + jl;
  int jj = 512 + j;
  float gpre = pa0[jj] + pa1[jj] + pa2[jj] + pa3[jj] + b_fb[j];
  xh_awe[(size_t)b_*2048 + j] = f2bf(sigm(gpre)*s);
}

// ---------------- fused gates GEMM + LSTM cell: 128 blocks x 512 threads ----------------
// block j owns 16 output cols {g*512 + j*4 + c : g<4, c<4}; K=3072 split across 8 waves (384 each)
__global__ __launch_bounds__(512) void k_gatecell(const bf16_t* __restrict__ embT,
    const bf16_t* __restrict__ xh_awe, const bf16_t* __restrict__ hr,
    bf16_t* __restrict__ hw, const bf16_t* __restrict__ Wcat,
    const float* __restrict__ b_ih, const float* __restrict__ b_hh,
    float* __restrict__ cbuf, bf16_t* __restrict__ h2all,
    const int* __restrict__ dlen, int t){
  __shared__ float part[8][64][16];
  int j = blockIdx.x, tid = threadIdx.x;
  int w = tid>>6, l = tid&63;
  int n_ = l&15;
  int wrow = (n_>>2)*512 + j*4 + (n_&3);
  const bf16_t* wp = Wcat + (size_t)wrow*3072;
  f32x4 acc[4] = {};
  int k0w = w*384;
  for(int kk=0;kk<12;kk++){
    int col = k0w + kk*32 + (l>>4)*8;
    bf16x8 af[4], bg;
    if(col < 512){
      #pragma unroll
      for(int m=0;m<4;m++) af[m] = *(const bf16x8*)(embT + (size_t)(16*m + n_)*512 + col);
    } else if(col < 2560){
      #pragma unroll
      for(int m=0;m<4;m++) af[m] = *(const bf16x8*)(xh_awe + (size_t)(16*m + n_)*2048 + col - 512);
    } else {
      #pragma unroll
      for(int m=0;m<4;m++) af[m] = *(const bf16x8*)(hr + (size_t)(16*m + n_)*512 + col - 2560);
    }
    bg = *(const bf16x8*)(wp + col);
    #pragma unroll
    for(int m=0;m<4;m++)
      acc[m] = __builtin_amdgcn_mfma_f32_16x16x32_bf16(af[m], bg, acc[m], 0,0,0);
  }
  #pragma unroll
  for(int m=0;m<4;m++)
    #pragma unroll
    for(int r=0;r<4;r++)
      part[w][16*m + (l>>4)*4 + r][n_] = acc[m][r];
  __syncthreads();
  // cell: threads 0..255, one output each (64 b x 4 c), sum 8 partials
  if(tid < 256){
    int b = tid>>2, c = tid&3;
    int dg = j*4 + c;
    float gs[4];
    #pragma unroll
    for(int g=0;g<4;g++){
      float s = b_ih[g*512+dg] + b_hh[g*512+dg];
      #pragma unroll
      for(int ww=0;ww<8;ww++) s += part[ww][b][g*4+c];
      gs[g] = s;
    }
    float oldc = cbuf[b*512 + dg];
    float c2 = sigm(gs[1])*oldc + sigm(gs[0])*tanhf(gs[2]);
    float h2 = sigm(gs[3])*tanhf(c2);
    bool mk = t < dlen[b];
    if(mk) cbuf[b*512 + dg] = c2;
    hw[(size_t)b*512 + dg] = mk ? f2bf(h2) : hr[(size_t)b*512 + dg];
    h2all[((size_t)t*NB + b)*512 + dg] = f2bf(h2);
  }
}

// ---------------- launcher ----------------
extern "C" void kernel_launch(void* const* d_in, const int* in_sizes, int n_in,
                              void* d_out, int out_size, void* d_ws, size_t ws_size,
                              hipStream_t stream){
  (void)in_sizes; (void)n_in; (void)out_size; (void)ws_size;
  const float* encoder_out      = (const float*)d_in[0];
  const int*   encoded_captions = (const int*)d_in[1];
  const int*   caption_lengths  = (const int*)d_in[2];
  const float* W_ea = (const float*)d_in[3];  const float* b_ea = (const float*)d_in[4];
  const float* W_da = (const float*)d_in[5];  const float* b_da = (const float*)d_in[6];
  const float* w_fa = (const float*)d_in[7];  const float* b_fa = (const float*)d_in[8];
  const float* emb_table = (const float*)d_in[9];
  const float* W_ih = (const float*)d_in[10]; const float* b_ih = (const float*)d_in[11];
  const float* W_hh = (const float*)d_in[12]; const float* b_hh = (const float*)d_in[13];
  const float* W_init_h = (const float*)d_in[14]; const float* b_init_h = (const float*)d_in[15];
  const float* W_init_c = (const float*)d_in[16]; const float* b_init_c = (const float*)d_in[17];
  const float* W_fb = (const float*)d_in[18]; const float* b_fb = (const float*)d_in[19];
  const float* W_fc = (const float*)d_in[20]; const float* b_fc = (const float*)d_in[21];

  // d_out layout (all f32): preds | caps | dec_len | alphas | order
  float* out_preds = (float*)d_out;
  float* out_caps  = out_preds + (size_t)NB*NT*NV;
  float* out_dlen  = out_caps + NB*NL;
  float* out_alph  = out_dlen + NB;
  float* out_order = out_alph + (size_t)NB*NT*NP;

  char* ws = (char*)d_ws;
  size_t off = 0;
  auto alloc = [&](size_t bytes)->size_t{ size_t r = off; off += (bytes + 255) & ~(size_t)255; return r; };
  bf16_t* enc_b   = (bf16_t*)(ws + alloc((size_t)12544*2048*2));
  char*   reg_att1 = ws + alloc((size_t)12544*512*2);       // att1_b; ipart overlaps (setup-only, pre-att1)
  bf16_t* att1_b  = (bf16_t*)reg_att1;
  float*  ipart   = (float*)reg_att1;
  char*   reg_h2   = ws + alloc((size_t)3328*512*2);        // h2all; Wea_b overlaps (setup-only)
  bf16_t* h2all_b = (bf16_t*)reg_h2;
  bf16_t* Wea_b   = (bf16_t*)reg_h2;
  bf16_t* Wdafb_b = (bf16_t*)(ws + alloc((size_t)2560*512*2));
  bf16_t* Wcat_b  = (bf16_t*)(ws + alloc((size_t)2048*3072*2));
  bf16_t* Wfc_b   = (bf16_t*)(ws + alloc((size_t)10000*512*2));
  char*   reg_wi  = ws + alloc((size_t)1024*2048*2);        // Winit (setup) / embAll (loop) overlap
  bf16_t* Winit_b = (bf16_t*)reg_wi;
  bf16_t* embAll  = (bf16_t*)reg_wi;                         // 51*64*512*2 = 3.34MB <= 4.19MB
  bf16_t* me_b    = (bf16_t*)(ws + alloc((size_t)64*2048*2));
  bf16_t* xh_awe  = (bf16_t*)(ws + alloc((size_t)64*2048*2));
  bf16_t* hbuf0   = (bf16_t*)(ws + alloc((size_t)64*512*2));
  bf16_t* hbuf1   = (bf16_t*)(ws + alloc((size_t)64*512*2));
  float*  c_f     = (float*)(ws + alloc((size_t)64*512*4));
  float*  a2gp_f  = (float*)(ws + alloc((size_t)4*64*2560*4));
  float*  e_f     = (float*)(ws + alloc((size_t)64*196*4));
  int*    order_i = (int*)(ws + alloc(64*4));
  int*    dlen_i  = (int*)(ws + alloc(64*4));
  int*    nact_i  = (int*)(ws + alloc(64*4));
  int*    caps_i  = (int*)(ws + alloc((size_t)64*52*4));

  k_sort<<<1,64,0,stream>>>(caption_lengths, encoded_captions, order_i, dlen_i, caps_i, nact_i,
                            out_caps, out_dlen, out_order);
  k_cvt4<<<2048,256,0,stream>>>(encoder_out, enc_b, 12544*2048/4);

  // merged weight conversions: 8 regions, one dispatch
  CvtRegs R;
  int n4s[8];
  R.src[0] = W_ea;      R.dst[0] = Wea_b;               n4s[0] = 512*2048/4;  R.cols4[0] = 512; R.dld[0] = 2048;
  R.src[1] = W_da;      R.dst[1] = Wdafb_b;             n4s[1] = 512*512/4;   R.cols4[1] = 128; R.dld[1] = 512;
  R.src[2] = W_fb;      R.dst[2] = Wdafb_b + 512*512;   n4s[2] = 2048*512/4;  R.cols4[2] = 128; R.dld[2] = 512;
  R.src[3] = W_ih;      R.dst[3] = Wcat_b;              n4s[3] = 2048*2560/4; R.cols4[3] = 640; R.dld[3] = 3072;
  R.src[4] = W_hh;      R.dst[4] = Wcat_b + 2560;       n4s[4] = 2048*512/4;  R.cols4[4] = 128; R.dld[4] = 3072;
  R.src[5] = W_init_h;  R.dst[5] = Winit_b;             n4s[5] = 512*2048/4;  R.cols4[5] = 512; R.dld[5] = 2048;
  R.src[6] = W_init_c;  R.dst[6] = Winit_b + 512*2048;  n4s[6] = 512*2048/4;  R.cols4[6] = 512; R.dld[6] = 2048;
  R.src[7] = W_fc;      R.dst[7] = Wfc_b;               n4s[7] = 10000*512/4; R.cols4[7] = 128; R.dld[7] = 512;
  R.start[0] = 0;
  for(int i=0;i<8;i++) R.start[i+1] = R.start[i] + n4s[i];
  k_cvtw<<<1024,256,0,stream>>>(R, R.start[8]);

  k_mean<<<dim3(64,8),256,0,stream>>>(enc_b, order_i, me_b);
  k_gemm_part<512><<<dim3(4,4),256,0,stream>>>(me_b, 2048, Winit_b, 2048, ipart, 1024);
  k_init_fin<<<128,256,0,stream>>>(ipart, b_init_h, b_init_c, c_f, hbuf0);
  // embAll overwrites Winit region — after init GEMM consumed Winit
  k_emb<<<dim3(NB,NT),256,0,stream>>>(caps_i, emb_table, embAll);
  // att1: XCD-swizzled 1D grid 392
  k_big<0><<<392,256,0,stream>>>(enc_b, 2048, 2048, Wea_b, 512, b_ea, nullptr, att1_b, nullptr);
  // initial a2g partials from h0 (4-way K-split)
  k_gemm_part<128><<<dim3(10,4),256,0,stream>>>(hbuf0, 512, Wdafb_b, 512, a2gp_f, 2560);

  bf16_t* hb[2] = { hbuf0, hbuf1 };
  for(int t=0;t<NT;t++){
    bf16_t* hr = hb[t&1];
    bf16_t* hw = hb[(t&1)^1];
    k_e<<<dim3(64,4),256,0,stream>>>(att1_b, a2gp_f, b_da, w_fa, b_fa, order_i, nact_i, e_f, t);
    k_awe<<<dim3(64,4),512,0,stream>>>(enc_b, e_f, a2gp_f, b_fb, order_i, nact_i,
                                       out_alph, xh_awe, t);
    k_gatecell<<<128,512,0,stream>>>(embAll + (size_t)t*NB*512, xh_awe, hr, hw, Wcat_b,
                                     b_ih, b_hh, c_f, h2all_b, dlen_i, t);
    k_gemm_part<128><<<dim3(10,4),256,0,stream>>>(hw, 512, Wdafb_b, 512, a2gp_f, 2560);
  }
  // deferred preds GEMM: XCD-swizzled 1D grid 2054
  k_big<2><<<2054,256,0,stream>>>(h2all_b, 512, 512, Wfc_b, NV, b_fc, out_preds, nullptr, dlen_i);
}

// Round 15
// 2341.540 us; speedup vs baseline: 2.1233x; 1.0737x over previous
//
#include <hip/hip_runtime.h>
#include <cmath>

#define NB 64
#define NP 196
#define NE 2048
#define NV 10000
#define NL 52
#define NT 51

typedef unsigned short bf16_t;
typedef __attribute__((ext_vector_type(8))) short bf16x8;
typedef __attribute__((ext_vector_type(4))) float f32x4;

__device__ inline unsigned short f2bf(float f){
  unsigned int x = __float_as_uint(f);
  unsigned int r = x + 0x7fffu + ((x>>16)&1u);
  return (unsigned short)(r>>16);
}
__device__ inline float bf2f(unsigned short u){ return __uint_as_float(((unsigned int)u)<<16); }
__device__ inline float sigm(float x){ return 1.f/(1.f+expf(-x)); }

// ---------------- sort (stable descending by length) + nact ----------------
__global__ void k_sort(const int* __restrict__ cap_len, const int* __restrict__ caps,
                       int* __restrict__ order, int* __restrict__ dlen, int* __restrict__ caps_s,
                       int* __restrict__ nact,
                       float* __restrict__ out_caps, float* __restrict__ out_dlen, float* __restrict__ out_order){
  __shared__ int len_s[NB];
  __shared__ int ord_s[NB];
  __shared__ int dls[NB];
  int t = threadIdx.x; // 64 threads
  len_s[t] = cap_len[t];
  __syncthreads();
  int li = len_s[t]; int rank = 0;
  for(int j=0;j<NB;j++){ int lj = len_s[j]; rank += ((lj > li) || (lj==li && j<t)) ? 1 : 0; }
  ord_s[rank] = t;
  __syncthreads();
  int ob = ord_s[t];
  order[t] = ob; out_order[t] = (float)ob;
  int ls = len_s[ob]; dlen[t] = ls-1; out_dlen[t] = (float)(ls-1); dls[t] = ls-1;
  for(int l=0;l<NL;l++){ int cv = caps[ob*NL + l]; caps_s[t*NL+l]=cv; out_caps[t*NL+l] = (float)cv; }
  __syncthreads();
  if(t < NT){
    int cnt=0;
    for(int b=0;b<NB;b++) cnt += (dls[b] > t) ? 1 : 0;
    nact[t] = cnt;
  }
}

// ---------------- all conversions (enc + 8 weight regions) in one dispatch ----------------
struct CvtRegs {
  const float* src[9];
  bf16_t* dst[9];
  int start[10];  // prefix offsets in f4 units
  int cols4[9];   // src row length / 4
  int dld[9];     // dst row stride (elements)
};

__global__ __launch_bounds__(256) void k_cvtw(CvtRegs R, int total4){
  int gid = blockIdx.x*blockDim.x + threadIdx.x;
  int stride = gridDim.x*blockDim.x;
  for(; gid<total4; gid+=stride){
    int rgn = 0;
    while(gid >= R.start[rgn+1]) rgn++;
    int i = gid - R.start[rgn];
    int c4n = R.cols4[rgn];
    int r = i / c4n, c4 = i - r*c4n;
    float4 v = ((const float4*)R.src[rgn])[i];
    unsigned long long p = (unsigned long long)f2bf(v.x)
        | ((unsigned long long)f2bf(v.y)<<16)
        | ((unsigned long long)f2bf(v.z)<<32)
        | ((unsigned long long)f2bf(v.w)<<48);
    *(unsigned long long*)(R.dst[rgn] + (size_t)r*R.dld[rgn] + c4*4) = p;
  }
}

// ---------------- mean over P from bf16 enc ----------------
__global__ __launch_bounds__(256) void k_mean(const bf16_t* __restrict__ encb, const int* __restrict__ order,
                                              bf16_t* __restrict__ me_s){
  int bs = blockIdx.x; int ec = blockIdx.y; int e = ec*256 + threadIdx.x;
  int ob = order[bs];
  const bf16_t* p = encb + (size_t)ob*NP*NE + e;
  float acc=0.f;
  for(int q=0;q<NP;q++) acc += bf2f(p[(size_t)q*NE]);
  me_s[(size_t)bs*NE + e] = f2bf(acc * (1.0f/NP));
}

// ---------------- embedding precompute: embAll[t][b][512] ----------------
__global__ __launch_bounds__(256) void k_emb(const int* __restrict__ caps_s, const float* __restrict__ emb_table,
                                             bf16_t* __restrict__ embAll){
  int b = blockIdx.x, t = blockIdx.y, tid = threadIdx.x;
  int cap = caps_s[b*NL + t];
  bf16_t* dst = embAll + ((size_t)t*NB + b)*512;
  const float* src = emb_table + (size_t)cap*512;
  dst[tid]       = f2bf(src[tid]);
  dst[tid + 256] = f2bf(src[tid + 256]);
}

// ---------------- big GEMM (128x128 tiles), XCD-swizzled 1D grid ----------------
// MODE0: att1 (bf16 out), grid 392. MODE2: preds (f32 out, masked, LDS-staged writes), grid 2054.
template<int MODE>
__global__ __launch_bounds__(256) void k_big(const bf16_t* __restrict__ A, int lda, int Kdim,
      const bf16_t* __restrict__ Bw, int nrowsB,
      const float* __restrict__ bias, float* __restrict__ outf, bf16_t* __restrict__ outb,
      const int* __restrict__ dlen){
  __shared__ __align__(16) char smem_raw[36864];
  bf16_t (*As)[72] = (bf16_t(*)[72])smem_raw;
  bf16_t (*Bs)[72] = (bf16_t(*)[72])(smem_raw + 18432);
  int lid = blockIdx.x;
  int nblk, mblk;
  if(MODE==0){
    int wg = (lid&7)*49 + (lid>>3);     // 392/8 = 49 exact
    mblk = wg>>2; nblk = wg&3;
  } else {
    int xcd = lid&7; int idx = lid>>3;  // 2054 = 8*256 + 6
    int wg = (xcd<6) ? xcd*257 + idx : 1542 + (xcd-6)*256 + idx;
    nblk = wg/26; mblk = wg - nblk*26;
  }
  int tid = threadIdx.x;
  int w = tid>>6, l = tid&63;
  int moff = (w>>1)*64, noff = (w&1)*64;
  f32x4 acc[4][4] = {};
  const int mbase = mblk*128, nbase = nblk*128;
  for(int k0=0; k0<Kdim; k0+=64){
    __syncthreads();
    for(int u=0;u<4;u++){
      int lin = u*256 + tid; int row = lin>>3; int col = (lin&7)*8;
      *(bf16x8*)(&As[row][col]) = *(const bf16x8*)(A + (size_t)(mbase+row)*lda + k0 + col);
      int rB = nbase+row; if(MODE==2 && rB >= nrowsB) rB = nrowsB-1;
      *(bf16x8*)(&Bs[row][col]) = *(const bf16x8*)(Bw + (size_t)rB*lda + k0 + col);
    }
    __syncthreads();
    for(int kk=0;kk<2;kk++){
      bf16x8 af[4], bfr[4];
      for(int m=0;m<4;m++) af[m] = *(bf16x8*)(&As[moff + 16*m + (l&15)][kk*32 + (l>>4)*8]);
      for(int n=0;n<4;n++) bfr[n] = *(bf16x8*)(&Bs[noff + 16*n + (l&15)][kk*32 + (l>>4)*8]);
      for(int m=0;m<4;m++)
        for(int n=0;n<4;n++)
          acc[m][n] = __builtin_amdgcn_mfma_f32_16x16x32_bf16(af[m], bfr[n], acc[m][n], 0,0,0);
    }
  }
  if(MODE==0){
    for(int m=0;m<4;m++) for(int n=0;n<4;n++){
      int col = nbase + noff + 16*n + (l&15);
      float bi = bias[col];
      for(int r=0;r<4;r++){
        int row = mbase + moff + 16*m + (l>>4)*4 + r;
        outb[(size_t)row*512 + col] = f2bf(acc[m][n][r] + bi);
      }
    }
  } else {
    float* st = (float*)smem_raw;  // 64*128*4 = 32768 <= 36864
    for(int h=0; h<2; ++h){
      __syncthreads();
      if((w>>1)==h){
        for(int m=0;m<4;m++) for(int n=0;n<4;n++)
          for(int r=0;r<4;r++)
            st[(16*m + (l>>4)*4 + r)*128 + noff + 16*n + (l&15)] = acc[m][n][r];
      }
      __syncthreads();
      for(int rr = tid>>5; rr<64; rr+=8){
        int row = mbase + h*64 + rr;
        if(row < NT*NB){
          int tt = row>>6, bb = row&63;
          int cc = (tid&31)*4;
          int col0 = nbase + cc;
          if(col0 < NV){
            float4 v = *(float4*)&st[rr*128 + cc];
            float4 bi4 = *(const float4*)&bias[col0];
            v.x+=bi4.x; v.y+=bi4.y; v.z+=bi4.z; v.w+=bi4.w;
            if(tt >= dlen[bb]){ v.x=0.f; v.y=0.f; v.z=0.f; v.w=0.f; }
            *(float4*)&outf[((size_t)bb*NT + tt)*NV + col0] = v;
          }
        }
      }
    }
  }
}

// ---------------- small-M (64) GEMM with K-split: partials ----------------
template<int KSL>
__global__ __launch_bounds__(256) void k_gemm_part(const bf16_t* __restrict__ Ax, int lda,
        const bf16_t* __restrict__ W, int ldw, float* __restrict__ part, int N){
  __shared__ bf16_t As[64][KSL+8];
  int ntile = blockIdx.x, ks = blockIdx.y;
  int tid = threadIdx.x; int w = tid>>6, l = tid&63;
  int k0 = ks*KSL;
  constexpr int UPR = KSL/8;
  constexpr int UPT = 64*UPR/256;
  for(int u=0;u<UPT;u++){
    int lin = u*256 + tid; int row = lin/UPR; int col = (lin%UPR)*8;
    *(bf16x8*)(&As[row][col]) = *(const bf16x8*)(Ax + (size_t)row*lda + k0 + col);
  }
  __syncthreads();
  f32x4 acc[4][4] = {};
  int nbase = ntile*256 + w*64;
  for(int kk=0; kk<KSL/32; kk++){
    bf16x8 af[4], bfr[4];
    for(int m=0;m<4;m++) af[m] = *(bf16x8*)(&As[16*m + (l&15)][kk*32 + (l>>4)*8]);
    for(int n=0;n<4;n++) bfr[n] = *(const bf16x8*)(W + (size_t)(nbase + 16*n + (l&15))*ldw + k0 + kk*32 + (l>>4)*8);
    for(int m=0;m<4;m++)
      for(int n=0;n<4;n++)
        acc[m][n] = __builtin_amdgcn_mfma_f32_16x16x32_bf16(af[m], bfr[n], acc[m][n], 0,0,0);
  }
  float* po = part + (size_t)ks*64*N;
  for(int m=0;m<4;m++) for(int n=0;n<4;n++){
    int col = nbase + 16*n + (l&15);
    for(int r=0;r<4;r++){
      int row = 16*m + (l>>4)*4 + r;
      po[(size_t)row*N + col] = acc[m][n][r];
    }
  }
}

// ---------------- combine init partials -> h0 (hbuf0), c0 ----------------
__global__ __launch_bounds__(256) void k_init_fin(const float* __restrict__ part,
        const float* __restrict__ b_ih_, const float* __restrict__ b_ic_,
        float* __restrict__ c, bf16_t* __restrict__ h0){
  int idx = blockIdx.x*256 + threadIdx.x;  // 0..32767
  int b_ = idx>>9, d = idx&511;
  float h = b_ih_[d], cc = b_ic_[d];
  for(int ks=0;ks<4;ks++){
    const float* p = part + (size_t)ks*64*1024 + (size_t)b_*1024;
    h += p[d]; cc += p[512+d];
  }
  c[idx] = cc;
  h0[(size_t)b_*512 + d] = f2bf(h);
}

// ---------------- e-scores: grid (64 b, 4 p-groups) x 512 (8 waves, 7 p-iters/wave) ----------------
__global__ __launch_bounds__(512) void k_e(const bf16_t* __restrict__ att1,
    const float* __restrict__ a2g, const float* __restrict__ b_da,
    const float* __restrict__ w_fa, const float* __restrict__ b_fa,
    const int* __restrict__ order, const int* __restrict__ nact,
    float* __restrict__ e_out, int t){
  int b_ = blockIdx.x, pg = blockIdx.y, tid = threadIdx.x;
  if(b_ >= nact[t]) return;
  int w = tid>>6, l = tid&63;
  int ob = order[b_];
  const float* pa0 = a2g + ((size_t)0*NB + b_)*2560;
  const float* pa1 = a2g + ((size_t)1*NB + b_)*2560;
  const float* pa2 = a2g + ((size_t)2*NB + b_)*2560;
  const float* pa3 = a2g + ((size_t)3*NB + b_)*2560;
  float ar[8], wr[8];
  #pragma unroll
  for(int q=0;q<8;q++){
    int i = l*8 + q;
    ar[q] = pa0[i] + pa1[i] + pa2[i] + pa3[i] + b_da[i];
    wr[q] = w_fa[i];
  }
  float bfa0 = b_fa[0];
  for(int pl=w; pl<49; pl+=8){
    int p = pg*49 + pl;
    bf16x8 a1v = *(const bf16x8*)(att1 + ((size_t)ob*NP + p)*512 + l*8);
    float s = 0.f;
    #pragma unroll
    for(int q=0;q<8;q++){
      float v = bf2f((unsigned short)a1v[q]) + ar[q];
      v = v>0.f ? v : 0.f;
      s += v*wr[q];
    }
    #pragma unroll
    for(int off=32;off;off>>=1) s += __shfl_down(s, off);
    if(l==0) e_out[b_*NP + p] = s + bfa0;
  }
}

// ---------------- softmax (8-wave) + awe (8-wave p-split) + gate: grid (64 b, 4 col-slices) x 512 ----------------
__global__ __launch_bounds__(512) void k_awe(const bf16_t* __restrict__ enc, const float* __restrict__ e_in,
    const float* __restrict__ a2g, const float* __restrict__ b_fb,
    const int* __restrict__ order, const int* __restrict__ nact,
    float* __restrict__ alphas_out, bf16_t* __restrict__ xh_awe, int t){
  int b_ = blockIdx.x, y = blockIdx.y, tid = threadIdx.x;
  if(b_ >= nact[t]){
    if(y==0 && tid<NP) alphas_out[((size_t)b_*NT + t)*NP + tid] = 0.f;
    return;
  }
  __shared__ float al[200];
  __shared__ float red[16];
  __shared__ float aw[8][512];
  int w = tid>>6, l = tid&63;
  // softmax over 196 with 8 waves (waves 4-7 carry -inf/0)
  float v = (tid<NP)? e_in[b_*NP + tid] : -1e30f;
  float m = v;
  #pragma unroll
  for(int off=32;off;off>>=1) m = fmaxf(m, __shfl_down(m, off));
  if(l==0) red[w] = m;
  __syncthreads();
  float mx = red[0];
  #pragma unroll
  for(int i=1;i<8;i++) mx = fmaxf(mx, red[i]);
  float ex = (tid<NP)? expf(v - mx) : 0.f;
  float s2 = ex;
  #pragma unroll
  for(int off=32;off;off>>=1) s2 += __shfl_down(s2, off);
  if(l==0) red[8+w] = s2;
  __syncthreads();
  float sum = red[8];
  #pragma unroll
  for(int i=9;i<16;i++) sum += red[i];
  float inv = 1.f/sum;
  if(tid<NP){
    float a = ex*inv;
    al[tid] = a;
    if(y==0) alphas_out[((size_t)b_*NT + t)*NP + tid] = a;
  }
  __syncthreads();
  // awe for cols [y*512, y*512+512): wave w takes strided p (25 iters max), lane covers 8 cols
  int ob = order[b_];
  int j0 = y*512 + l*8;
  float a8[8] = {};
  const bf16_t* ep = enc + (size_t)ob*NP*NE + j0;
  for(int p=w; p<NP; p+=8){
    bf16x8 ev = *(const bf16x8*)(ep + (size_t)p*NE);
    float alp = al[p];
    #pragma unroll
    for(int q=0;q<8;q++) a8[q] += alp*bf2f((unsigned short)ev[q]);
  }
  #pragma unroll
  for(int q=0;q<8;q++) aw[w][l*8 + q] = a8[q];
  __syncthreads();
  // combine 8 p-partials + gate, write bf16 (1 col/thread)
  const float* pa0 = a2g + ((size_t)0*NB + b_)*2560;
  const float* pa1 = a2g + ((size_t)1*NB + b_)*2560;
  const float* pa2 = a2g + ((size_t)2*NB + b_)*2560;
  const float* pa3 = a2g + ((size_t)3*NB + b_)*2560;
  int jl = tid;   // 0..511
  float s = aw[0][jl] + aw[1][jl] + aw[2][jl] + aw[3][jl]
          + aw[4][jl] + aw[5][jl] + aw[6][jl] + aw[7][jl];
  int j  = y*512 + jl;
  int jj = 512 + j;
  float gpre = pa0[jj] + pa1[jj] + pa2[jj] + pa3[jj] + b_fb[j];
  xh_awe[(size_t)b_*2048 + j] = f2bf(sigm(gpre)*s);
}

// ---------------- fused gates GEMM + LSTM cell: 128 blocks x 512 threads ----------------
// block j owns 16 output cols {g*512 + j*4 + c : g<4, c<4}; K=3072 split across 8 waves (384 each)
__global__ __launch_bounds__(512) void k_gatecell(const bf16_t* __restrict__ embT,
    const bf16_t* __restrict__ xh_awe, const bf16_t* __restrict__ hr,
    bf16_t* __restrict__ hw, const bf16_t* __restrict__ Wcat,
    const float* __restrict__ b_ih, const float* __restrict__ b_hh,
    float* __restrict__ cbuf, bf16_t* __restrict__ h2all,
    const int* __restrict__ dlen, int t){
  __shared__ float part[8][64][16];
  int j = blockIdx.x, tid = threadIdx.x;
  int w = tid>>6, l = tid&63;
  int n_ = l&15;
  int wrow = (n_>>2)*512 + j*4 + (n_&3);
  const bf16_t* wp = Wcat + (size_t)wrow*3072;
  f32x4 acc[4] = {};
  int k0w = w*384;
  for(int kk=0;kk<12;kk++){
    int col = k0w + kk*32 + (l>>4)*8;
    bf16x8 af[4], bg;
    if(col < 512){
      #pragma unroll
      for(int m=0;m<4;m++) af[m] = *(const bf16x8*)(embT + (size_t)(16*m + n_)*512 + col);
    } else if(col < 2560){
      #pragma unroll
      for(int m=0;m<4;m++) af[m] = *(const bf16x8*)(xh_awe + (size_t)(16*m + n_)*2048 + col - 512);
    } else {
      #pragma unroll
      for(int m=0;m<4;m++) af[m] = *(const bf16x8*)(hr + (size_t)(16*m + n_)*512 + col - 2560);
    }
    bg = *(const bf16x8*)(wp + col);
    #pragma unroll
    for(int m=0;m<4;m++)
      acc[m] = __builtin_amdgcn_mfma_f32_16x16x32_bf16(af[m], bg, acc[m], 0,0,0);
  }
  #pragma unroll
  for(int m=0;m<4;m++)
    #pragma unroll
    for(int r=0;r<4;r++)
      part[w][16*m + (l>>4)*4 + r][n_] = acc[m][r];
  __syncthreads();
  // cell: threads 0..255, one output each (64 b x 4 c), sum 8 partials
  if(tid < 256){
    int b = tid>>2, c = tid&3;
    int dg = j*4 + c;
    float gs[4];
    #pragma unroll
    for(int g=0;g<4;g++){
      float s = b_ih[g*512+dg] + b_hh[g*512+dg];
      #pragma unroll
      for(int ww=0;ww<8;ww++) s += part[ww][b][g*4+c];
      gs[g] = s;
    }
    float oldc = cbuf[b*512 + dg];
    float c2 = sigm(gs[1])*oldc + sigm(gs[0])*tanhf(gs[2]);
    float h2 = sigm(gs[3])*tanhf(c2);
    bool mk = t < dlen[b];
    if(mk) cbuf[b*512 + dg] = c2;
    hw[(size_t)b*512 + dg] = mk ? f2bf(h2) : hr[(size_t)b*512 + dg];
    h2all[((size_t)t*NB + b)*512 + dg] = f2bf(h2);
  }
}

// ---------------- launcher ----------------
extern "C" void kernel_launch(void* const* d_in, const int* in_sizes, int n_in,
                              void* d_out, int out_size, void* d_ws, size_t ws_size,
                              hipStream_t stream){
  (void)in_sizes; (void)n_in; (void)out_size; (void)ws_size;
  const float* encoder_out      = (const float*)d_in[0];
  const int*   encoded_captions = (const int*)d_in[1];
  const int*   caption_lengths  = (const int*)d_in[2];
  const float* W_ea = (const float*)d_in[3];  const float* b_ea = (const float*)d_in[4];
  const float* W_da = (const float*)d_in[5];  const float* b_da = (const float*)d_in[6];
  const float* w_fa = (const float*)d_in[7];  const float* b_fa = (const float*)d_in[8];
  const float* emb_table = (const float*)d_in[9];
  const float* W_ih = (const float*)d_in[10]; const float* b_ih = (const float*)d_in[11];
  const float* W_hh = (const float*)d_in[12]; const float* b_hh = (const float*)d_in[13];
  const float* W_init_h = (const float*)d_in[14]; const float* b_init_h = (const float*)d_in[15];
  const float* W_init_c = (const float*)d_in[16]; const float* b_init_c = (const float*)d_in[17];
  const float* W_fb = (const float*)d_in[18]; const float* b_fb = (const float*)d_in[19];
  const float* W_fc = (const float*)d_in[20]; const float* b_fc = (const float*)d_in[21];

  // d_out layout (all f32): preds | caps | dec_len | alphas | order
  float* out_preds = (float*)d_out;
  float* out_caps  = out_preds + (size_t)NB*NT*NV;
  float* out_dlen  = out_caps + NB*NL;
  float* out_alph  = out_dlen + NB;
  float* out_order = out_alph + (size_t)NB*NT*NP;

  char* ws = (char*)d_ws;
  size_t off = 0;
  auto alloc = [&](size_t bytes)->size_t{ size_t r = off; off += (bytes + 255) & ~(size_t)255; return r; };
  bf16_t* enc_b   = (bf16_t*)(ws + alloc((size_t)12544*2048*2));
  char*   reg_att1 = ws + alloc((size_t)12544*512*2);       // att1_b; ipart overlaps (setup-only, pre-att1)
  bf16_t* att1_b  = (bf16_t*)reg_att1;
  float*  ipart   = (float*)reg_att1;
  char*   reg_h2   = ws + alloc((size_t)3328*512*2);        // h2all; Wea_b overlaps (setup-only)
  bf16_t* h2all_b = (bf16_t*)reg_h2;
  bf16_t* Wea_b   = (bf16_t*)reg_h2;
  bf16_t* Wdafb_b = (bf16_t*)(ws + alloc((size_t)2560*512*2));
  bf16_t* Wcat_b  = (bf16_t*)(ws + alloc((size_t)2048*3072*2));
  bf16_t* Wfc_b   = (bf16_t*)(ws + alloc((size_t)10000*512*2));
  char*   reg_wi  = ws + alloc((size_t)1024*2048*2);        // Winit (setup) / embAll (loop) overlap
  bf16_t* Winit_b = (bf16_t*)reg_wi;
  bf16_t* embAll  = (bf16_t*)reg_wi;                         // 51*64*512*2 = 3.34MB <= 4.19MB
  bf16_t* me_b    = (bf16_t*)(ws + alloc((size_t)64*2048*2));
  bf16_t* xh_awe  = (bf16_t*)(ws + alloc((size_t)64*2048*2));
  bf16_t* hbuf0   = (bf16_t*)(ws + alloc((size_t)64*512*2));
  bf16_t* hbuf1   = (bf16_t*)(ws + alloc((size_t)64*512*2));
  float*  c_f     = (float*)(ws + alloc((size_t)64*512*4));
  float*  a2gp_f  = (float*)(ws + alloc((size_t)4*64*2560*4));
  float*  e_f     = (float*)(ws + alloc((size_t)64*196*4));
  int*    order_i = (int*)(ws + alloc(64*4));
  int*    dlen_i  = (int*)(ws + alloc(64*4));
  int*    nact_i  = (int*)(ws + alloc(64*4));
  int*    caps_i  = (int*)(ws + alloc((size_t)64*52*4));

  k_sort<<<1,64,0,stream>>>(caption_lengths, encoded_captions, order_i, dlen_i, caps_i, nact_i,
                            out_caps, out_dlen, out_order);

  // merged conversions: enc + 8 weight regions, one dispatch
  CvtRegs R;
  int n4s[9];
  R.src[0] = encoder_out; R.dst[0] = enc_b;               n4s[0] = 12544*2048/4; R.cols4[0] = 512; R.dld[0] = 2048;
  R.src[1] = W_ea;      R.dst[1] = Wea_b;               n4s[1] = 512*2048/4;  R.cols4[1] = 512; R.dld[1] = 2048;
  R.src[2] = W_da;      R.dst[2] = Wdafb_b;             n4s[2] = 512*512/4;   R.cols4[2] = 128; R.dld[2] = 512;
  R.src[3] = W_fb;      R.dst[3] = Wdafb_b + 512*512;   n4s[3] = 2048*512/4;  R.cols4[3] = 128; R.dld[3] = 512;
  R.src[4] = W_ih;      R.dst[4] = Wcat_b;              n4s[4] = 2048*2560/4; R.cols4[4] = 640; R.dld[4] = 3072;
  R.src[5] = W_hh;      R.dst[5] = Wcat_b + 2560;       n4s[5] = 2048*512/4;  R.cols4[5] = 128; R.dld[5] = 3072;
  R.src[6] = W_init_h;  R.dst[6] = Winit_b;             n4s[6] = 512*2048/4;  R.cols4[6] = 512; R.dld[6] = 2048;
  R.src[7] = W_init_c;  R.dst[7] = Winit_b + 512*2048;  n4s[7] = 512*2048/4;  R.cols4[7] = 512; R.dld[7] = 2048;
  R.src[8] = W_fc;      R.dst[8] = Wfc_b;               n4s[8] = 10000*512/4; R.cols4[8] = 128; R.dld[8] = 512;
  R.start[0] = 0;
  for(int i=0;i<9;i++) R.start[i+1] = R.start[i] + n4s[i];
  k_cvtw<<<2048,256,0,stream>>>(R, R.start[9]);

  k_mean<<<dim3(64,8),256,0,stream>>>(enc_b, order_i, me_b);
  k_gemm_part<512><<<dim3(4,4),256,0,stream>>>(me_b, 2048, Winit_b, 2048, ipart, 1024);
  k_init_fin<<<128,256,0,stream>>>(ipart, b_init_h, b_init_c, c_f, hbuf0);
  // embAll overwrites Winit region — after init GEMM consumed Winit
  k_emb<<<dim3(NB,NT),256,0,stream>>>(caps_i, emb_table, embAll);
  // att1: XCD-swizzled 1D grid 392
  k_big<0><<<392,256,0,stream>>>(enc_b, 2048, 2048, Wea_b, 512, b_ea, nullptr, att1_b, nullptr);
  // initial a2g partials from h0 (4-way K-split)
  k_gemm_part<128><<<dim3(10,4),256,0,stream>>>(hbuf0, 512, Wdafb_b, 512, a2gp_f, 2560);

  bf16_t* hb[2] = { hbuf0, hbuf1 };
  for(int t=0;t<NT;t++){
    bf16_t* hr = hb[t&1];
    bf16_t* hw = hb[(t&1)^1];
    k_e<<<dim3(64,4),512,0,stream>>>(att1_b, a2gp_f, b_da, w_fa, b_fa, order_i, nact_i, e_f, t);
    k_awe<<<dim3(64,4),512,0,stream>>>(enc_b, e_f, a2gp_f, b_fb, order_i, nact_i,
                                       out_alph, xh_awe, t);
    k_gatecell<<<128,512,0,stream>>>(embAll + (size_t)t*NB*512, xh_awe, hr, hw, Wcat_b,
                                     b_ih, b_hh, c_f, h2all_b, dlen_i, t);
    k_gemm_part<128><<<dim3(10,4),256,0,stream>>>(hw, 512, Wdafb_b, 512, a2gp_f, 2560);
  }
  // deferred preds GEMM: XCD-swizzled 1D grid 2054
  k_big<2><<<2054,256,0,stream>>>(h2all_b, 512, 512, Wfc_b, NV, b_fc, out_preds, nullptr, dlen_i);
}

// Round 16
// 2325.899 us; speedup vs baseline: 2.1376x; 1.0067x over previous
//
#include <hip/hip_runtime.h>
#include <cmath>

#define NB 64
#define NP 196
#define NE 2048
#define NV 10000
#define NL 52
#define NT 51

typedef unsigned short bf16_t;
typedef __attribute__((ext_vector_type(8))) short bf16x8;
typedef __attribute__((ext_vector_type(4))) float f32x4;

__device__ inline unsigned short f2bf(float f){
  unsigned int x = __float_as_uint(f);
  unsigned int r = x + 0x7fffu + ((x>>16)&1u);
  return (unsigned short)(r>>16);
}
__device__ inline float bf2f(unsigned short u){ return __uint_as_float(((unsigned int)u)<<16); }
__device__ inline float sigm(float x){ return 1.f/(1.f+expf(-x)); }

// ---------------- sort (stable descending by length) + nact ----------------
__global__ void k_sort(const int* __restrict__ cap_len, const int* __restrict__ caps,
                       int* __restrict__ order, int* __restrict__ dlen, int* __restrict__ caps_s,
                       int* __restrict__ nact,
                       float* __restrict__ out_caps, float* __restrict__ out_dlen, float* __restrict__ out_order){
  __shared__ int len_s[NB];
  __shared__ int ord_s[NB];
  __shared__ int dls[NB];
  int t = threadIdx.x; // 64 threads
  len_s[t] = cap_len[t];
  __syncthreads();
  int li = len_s[t]; int rank = 0;
  for(int j=0;j<NB;j++){ int lj = len_s[j]; rank += ((lj > li) || (lj==li && j<t)) ? 1 : 0; }
  ord_s[rank] = t;
  __syncthreads();
  int ob = ord_s[t];
  order[t] = ob; out_order[t] = (float)ob;
  int ls = len_s[ob]; dlen[t] = ls-1; out_dlen[t] = (float)(ls-1); dls[t] = ls-1;
  for(int l=0;l<NL;l++){ int cv = caps[ob*NL + l]; caps_s[t*NL+l]=cv; out_caps[t*NL+l] = (float)cv; }
  __syncthreads();
  if(t < NT){
    int cnt=0;
    for(int b=0;b<NB;b++) cnt += (dls[b] > t) ? 1 : 0;
    nact[t] = cnt;
  }
}

// ---------------- all conversions (enc + 8 weight regions) in one dispatch ----------------
struct CvtRegs {
  const float* src[9];
  bf16_t* dst[9];
  int start[10];  // prefix offsets in f4 units
  int cols4[9];   // src row length / 4
  int dld[9];     // dst row stride (elements)
};

__global__ __launch_bounds__(256) void k_cvtw(CvtRegs R, int total4){
  int gid = blockIdx.x*blockDim.x + threadIdx.x;
  int stride = gridDim.x*blockDim.x;
  for(; gid<total4; gid+=stride){
    int rgn = 0;
    while(gid >= R.start[rgn+1]) rgn++;
    int i = gid - R.start[rgn];
    int c4n = R.cols4[rgn];
    int r = i / c4n, c4 = i - r*c4n;
    float4 v = ((const float4*)R.src[rgn])[i];
    unsigned long long p = (unsigned long long)f2bf(v.x)
        | ((unsigned long long)f2bf(v.y)<<16)
        | ((unsigned long long)f2bf(v.z)<<32)
        | ((unsigned long long)f2bf(v.w)<<48);
    *(unsigned long long*)(R.dst[rgn] + (size_t)r*R.dld[rgn] + c4*4) = p;
  }
}

// ---------------- mean over P from bf16 enc ----------------
__global__ __launch_bounds__(256) void k_mean(const bf16_t* __restrict__ encb, const int* __restrict__ order,
                                              bf16_t* __restrict__ me_s){
  int bs = blockIdx.x; int ec = blockIdx.y; int e = ec*256 + threadIdx.x;
  int ob = order[bs];
  const bf16_t* p = encb + (size_t)ob*NP*NE + e;
  float acc=0.f;
  for(int q=0;q<NP;q++) acc += bf2f(p[(size_t)q*NE]);
  me_s[(size_t)bs*NE + e] = f2bf(acc * (1.0f/NP));
}

// ---------------- embedding precompute: embAll[t][b][512] ----------------
__global__ __launch_bounds__(256) void k_emb(const int* __restrict__ caps_s, const float* __restrict__ emb_table,
                                             bf16_t* __restrict__ embAll){
  int b = blockIdx.x, t = blockIdx.y, tid = threadIdx.x;
  int cap = caps_s[b*NL + t];
  bf16_t* dst = embAll + ((size_t)t*NB + b)*512;
  const float* src = emb_table + (size_t)cap*512;
  dst[tid]       = f2bf(src[tid]);
  dst[tid + 256] = f2bf(src[tid + 256]);
}

// ---------------- big GEMM (128x128 tiles), XCD-swizzled 1D grid ----------------
// MODE0: att1 (bf16 out), grid 392. MODE2: preds (f32 out, masked, LDS-staged writes), grid 2054.
template<int MODE>
__global__ __launch_bounds__(256) void k_big(const bf16_t* __restrict__ A, int lda, int Kdim,
      const bf16_t* __restrict__ Bw, int nrowsB,
      const float* __restrict__ bias, float* __restrict__ outf, bf16_t* __restrict__ outb,
      const int* __restrict__ dlen){
  __shared__ __align__(16) char smem_raw[36864];
  bf16_t (*As)[72] = (bf16_t(*)[72])smem_raw;
  bf16_t (*Bs)[72] = (bf16_t(*)[72])(smem_raw + 18432);
  int lid = blockIdx.x;
  int nblk, mblk;
  if(MODE==0){
    int wg = (lid&7)*49 + (lid>>3);     // 392/8 = 49 exact
    mblk = wg>>2; nblk = wg&3;
  } else {
    int xcd = lid&7; int idx = lid>>3;  // 2054 = 8*256 + 6
    int wg = (xcd<6) ? xcd*257 + idx : 1542 + (xcd-6)*256 + idx;
    nblk = wg/26; mblk = wg - nblk*26;
  }
  int tid = threadIdx.x;
  int w = tid>>6, l = tid&63;
  int moff = (w>>1)*64, noff = (w&1)*64;
  f32x4 acc[4][4] = {};
  const int mbase = mblk*128, nbase = nblk*128;
  for(int k0=0; k0<Kdim; k0+=64){
    __syncthreads();
    for(int u=0;u<4;u++){
      int lin = u*256 + tid; int row = lin>>3; int col = (lin&7)*8;
      *(bf16x8*)(&As[row][col]) = *(const bf16x8*)(A + (size_t)(mbase+row)*lda + k0 + col);
      int rB = nbase+row; if(MODE==2 && rB >= nrowsB) rB = nrowsB-1;
      *(bf16x8*)(&Bs[row][col]) = *(const bf16x8*)(Bw + (size_t)rB*lda + k0 + col);
    }
    __syncthreads();
    for(int kk=0;kk<2;kk++){
      bf16x8 af[4], bfr[4];
      for(int m=0;m<4;m++) af[m] = *(bf16x8*)(&As[moff + 16*m + (l&15)][kk*32 + (l>>4)*8]);
      for(int n=0;n<4;n++) bfr[n] = *(bf16x8*)(&Bs[noff + 16*n + (l&15)][kk*32 + (l>>4)*8]);
      for(int m=0;m<4;m++)
        for(int n=0;n<4;n++)
          acc[m][n] = __builtin_amdgcn_mfma_f32_16x16x32_bf16(af[m], bfr[n], acc[m][n], 0,0,0);
    }
  }
  if(MODE==0){
    for(int m=0;m<4;m++) for(int n=0;n<4;n++){
      int col = nbase + noff + 16*n + (l&15);
      float bi = bias[col];
      for(int r=0;r<4;r++){
        int row = mbase + moff + 16*m + (l>>4)*4 + r;
        outb[(size_t)row*512 + col] = f2bf(acc[m][n][r] + bi);
      }
    }
  } else {
    float* st = (float*)smem_raw;  // 64*128*4 = 32768 <= 36864
    for(int h=0; h<2; ++h){
      __syncthreads();
      if((w>>1)==h){
        for(int m=0;m<4;m++) for(int n=0;n<4;n++)
          for(int r=0;r<4;r++)
            st[(16*m + (l>>4)*4 + r)*128 + noff + 16*n + (l&15)] = acc[m][n][r];
      }
      __syncthreads();
      for(int rr = tid>>5; rr<64; rr+=8){
        int row = mbase + h*64 + rr;
        if(row < NT*NB){
          int tt = row>>6, bb = row&63;
          int cc = (tid&31)*4;
          int col0 = nbase + cc;
          if(col0 < NV){
            float4 v = *(float4*)&st[rr*128 + cc];
            float4 bi4 = *(const float4*)&bias[col0];
            v.x+=bi4.x; v.y+=bi4.y; v.z+=bi4.z; v.w+=bi4.w;
            if(tt >= dlen[bb]){ v.x=0.f; v.y=0.f; v.z=0.f; v.w=0.f; }
            *(float4*)&outf[((size_t)bb*NT + tt)*NV + col0] = v;
          }
        }
      }
    }
  }
}

// ---------------- small-M (64) GEMM with K-split: partials ----------------
template<int KSL>
__global__ __launch_bounds__(256) void k_gemm_part(const bf16_t* __restrict__ Ax, int lda,
        const bf16_t* __restrict__ W, int ldw, float* __restrict__ part, int N){
  __shared__ bf16_t As[64][KSL+8];
  int ntile = blockIdx.x, ks = blockIdx.y;
  int tid = threadIdx.x; int w = tid>>6, l = tid&63;
  int k0 = ks*KSL;
  constexpr int UPR = KSL/8;
  constexpr int UPT = 64*UPR/256;
  for(int u=0;u<UPT;u++){
    int lin = u*256 + tid; int row = lin/UPR; int col = (lin%UPR)*8;
    *(bf16x8*)(&As[row][col]) = *(const bf16x8*)(Ax + (size_t)row*lda + k0 + col);
  }
  __syncthreads();
  f32x4 acc[4][4] = {};
  int nbase = ntile*256 + w*64;
  for(int kk=0; kk<KSL/32; kk++){
    bf16x8 af[4], bfr[4];
    for(int m=0;m<4;m++) af[m] = *(bf16x8*)(&As[16*m + (l&15)][kk*32 + (l>>4)*8]);
    for(int n=0;n<4;n++) bfr[n] = *(const bf16x8*)(W + (size_t)(nbase + 16*n + (l&15))*ldw + k0 + kk*32 + (l>>4)*8);
    for(int m=0;m<4;m++)
      for(int n=0;n<4;n++)
        acc[m][n] = __builtin_amdgcn_mfma_f32_16x16x32_bf16(af[m], bfr[n], acc[m][n], 0,0,0);
  }
  float* po = part + (size_t)ks*64*N;
  for(int m=0;m<4;m++) for(int n=0;n<4;n++){
    int col = nbase + 16*n + (l&15);
    for(int r=0;r<4;r++){
      int row = 16*m + (l>>4)*4 + r;
      po[(size_t)row*N + col] = acc[m][n][r];
    }
  }
}

// ---------------- combine init partials -> h0 (hbuf0), c0 ----------------
__global__ __launch_bounds__(256) void k_init_fin(const float* __restrict__ part,
        const float* __restrict__ b_ih_, const float* __restrict__ b_ic_,
        float* __restrict__ c, bf16_t* __restrict__ h0){
  int idx = blockIdx.x*256 + threadIdx.x;  // 0..32767
  int b_ = idx>>9, d = idx&511;
  float h = b_ih_[d], cc = b_ic_[d];
  for(int ks=0;ks<4;ks++){
    const float* p = part + (size_t)ks*64*1024 + (size_t)b_*1024;
    h += p[d]; cc += p[512+d];
  }
  c[idx] = cc;
  h0[(size_t)b_*512 + d] = f2bf(h);
}

// ---------------- e-scores: grid (64 b, 4 p-groups) x 512 (8 waves, 7 p-iters/wave); 8 a2g partials ----------------
__global__ __launch_bounds__(512) void k_e(const bf16_t* __restrict__ att1,
    const float* __restrict__ a2g, const float* __restrict__ b_da,
    const float* __restrict__ w_fa, const float* __restrict__ b_fa,
    const int* __restrict__ order, const int* __restrict__ nact,
    float* __restrict__ e_out, int t){
  int b_ = blockIdx.x, pg = blockIdx.y, tid = threadIdx.x;
  if(b_ >= nact[t]) return;
  int w = tid>>6, l = tid&63;
  int ob = order[b_];
  float ar[8], wr[8];
  #pragma unroll
  for(int q=0;q<8;q++){
    int i = l*8 + q;
    float s = b_da[i];
    #pragma unroll
    for(int ks=0;ks<8;ks++) s += a2g[((size_t)ks*NB + b_)*2560 + i];
    ar[q] = s;
    wr[q] = w_fa[i];
  }
  float bfa0 = b_fa[0];
  for(int pl=w; pl<49; pl+=8){
    int p = pg*49 + pl;
    bf16x8 a1v = *(const bf16x8*)(att1 + ((size_t)ob*NP + p)*512 + l*8);
    float s = 0.f;
    #pragma unroll
    for(int q=0;q<8;q++){
      float v = bf2f((unsigned short)a1v[q]) + ar[q];
      v = v>0.f ? v : 0.f;
      s += v*wr[q];
    }
    #pragma unroll
    for(int off=32;off;off>>=1) s += __shfl_down(s, off);
    if(l==0) e_out[b_*NP + p] = s + bfa0;
  }
}

// ---------------- softmax (8-wave) + awe (8-wave p-split) + gate: grid (64 b, 4 col-slices) x 512 ----------------
__global__ __launch_bounds__(512) void k_awe(const bf16_t* __restrict__ enc, const float* __restrict__ e_in,
    const float* __restrict__ a2g, const float* __restrict__ b_fb,
    const int* __restrict__ order, const int* __restrict__ nact,
    float* __restrict__ alphas_out, bf16_t* __restrict__ xh_awe, int t){
  int b_ = blockIdx.x, y = blockIdx.y, tid = threadIdx.x;
  if(b_ >= nact[t]){
    if(y==0 && tid<NP) alphas_out[((size_t)b_*NT + t)*NP + tid] = 0.f;
    return;
  }
  __shared__ float al[200];
  __shared__ float red[16];
  __shared__ float aw[8][512];
  int w = tid>>6, l = tid&63;
  // softmax over 196 with 8 waves (waves 4-7 carry -inf/0)
  float v = (tid<NP)? e_in[b_*NP + tid] : -1e30f;
  float m = v;
  #pragma unroll
  for(int off=32;off;off>>=1) m = fmaxf(m, __shfl_down(m, off));
  if(l==0) red[w] = m;
  __syncthreads();
  float mx = red[0];
  #pragma unroll
  for(int i=1;i<8;i++) mx = fmaxf(mx, red[i]);
  float ex = (tid<NP)? expf(v - mx) : 0.f;
  float s2 = ex;
  #pragma unroll
  for(int off=32;off;off>>=1) s2 += __shfl_down(s2, off);
  if(l==0) red[8+w] = s2;
  __syncthreads();
  float sum = red[8];
  #pragma unroll
  for(int i=9;i<16;i++) sum += red[i];
  float inv = 1.f/sum;
  if(tid<NP){
    float a = ex*inv;
    al[tid] = a;
    if(y==0) alphas_out[((size_t)b_*NT + t)*NP + tid] = a;
  }
  __syncthreads();
  // awe for cols [y*512, y*512+512): wave w takes strided p (25 iters max), lane covers 8 cols
  int ob = order[b_];
  int j0 = y*512 + l*8;
  float a8[8] = {};
  const bf16_t* ep = enc + (size_t)ob*NP*NE + j0;
  for(int p=w; p<NP; p+=8){
    bf16x8 ev = *(const bf16x8*)(ep + (size_t)p*NE);
    float alp = al[p];
    #pragma unroll
    for(int q=0;q<8;q++) a8[q] += alp*bf2f((unsigned short)ev[q]);
  }
  #pragma unroll
  for(int q=0;q<8;q++) aw[w][l*8 + q] = a8[q];
  __syncthreads();
  // combine 8 p-partials + gate, write bf16 (1 col/thread); gpre sums 8 a2g partials
  int jl = tid;   // 0..511
  float s = aw[0][jl] + aw[1][jl] + aw[2][jl] + aw[3][jl]
          + aw[4][jl] + aw[5][jl] + aw[6][jl] + aw[7][jl];
  int j  = y*512 + jl;
  int jj = 512 + j;
  float gpre = b_fb[j];
  #pragma unroll
  for(int ks=0;ks<8;ks++) gpre += a2g[((size_t)ks*NB + b_)*2560 + jj];
  xh_awe[(size_t)b_*2048 + j] = f2bf(sigm(gpre)*s);
}

// ---------------- fused gates GEMM + LSTM cell: 256 blocks x 512 threads ----------------
// block j owns 8 output cols {g*512 + j*2 + c : g<4, c<2}; K=3072 split across 8 waves (384 each)
__global__ __launch_bounds__(512) void k_gatecell(const bf16_t* __restrict__ embT,
    const bf16_t* __restrict__ xh_awe, const bf16_t* __restrict__ hr,
    bf16_t* __restrict__ hw, const bf16_t* __restrict__ Wcat,
    const float* __restrict__ b_ih, const float* __restrict__ b_hh,
    float* __restrict__ cbuf, bf16_t* __restrict__ h2all,
    const int* __restrict__ dlen, int t){
  __shared__ float part[8][64][8];
  int j = blockIdx.x, tid = threadIdx.x;
  int w = tid>>6, l = tid&63;
  int n_ = l&15;
  int rowsel = n_&7;                                // n_>=8 duplicates (outputs ignored)
  int wrow = (rowsel>>1)*512 + j*2 + (rowsel&1);
  const bf16_t* wp = Wcat + (size_t)wrow*3072;
  f32x4 acc[4] = {};
  int k0w = w*384;
  for(int kk=0;kk<12;kk++){
    int col = k0w + kk*32 + (l>>4)*8;
    bf16x8 af[4], bg;
    if(col < 512){
      #pragma unroll
      for(int m=0;m<4;m++) af[m] = *(const bf16x8*)(embT + (size_t)(16*m + n_)*512 + col);
    } else if(col < 2560){
      #pragma unroll
      for(int m=0;m<4;m++) af[m] = *(const bf16x8*)(xh_awe + (size_t)(16*m + n_)*2048 + col - 512);
    } else {
      #pragma unroll
      for(int m=0;m<4;m++) af[m] = *(const bf16x8*)(hr + (size_t)(16*m + n_)*512 + col - 2560);
    }
    bg = *(const bf16x8*)(wp + col);
    #pragma unroll
    for(int m=0;m<4;m++)
      acc[m] = __builtin_amdgcn_mfma_f32_16x16x32_bf16(af[m], bg, acc[m], 0,0,0);
  }
  if(n_ < 8){
    #pragma unroll
    for(int m=0;m<4;m++)
      #pragma unroll
      for(int r=0;r<4;r++)
        part[w][16*m + (l>>4)*4 + r][n_] = acc[m][r];
  }
  __syncthreads();
  // cell: threads 0..127, one output each (64 b x 2 c), sum 8 partials
  if(tid < 128){
    int b = tid>>1, c = tid&1;
    int dg = j*2 + c;
    float gs[4];
    #pragma unroll
    for(int g=0;g<4;g++){
      float s = b_ih[g*512+dg] + b_hh[g*512+dg];
      #pragma unroll
      for(int ww=0;ww<8;ww++) s += part[ww][b][g*2+c];
      gs[g] = s;
    }
    float oldc = cbuf[b*512 + dg];
    float c2 = sigm(gs[1])*oldc + sigm(gs[0])*tanhf(gs[2]);
    float h2 = sigm(gs[3])*tanhf(c2);
    bool mk = t < dlen[b];
    if(mk) cbuf[b*512 + dg] = c2;
    hw[(size_t)b*512 + dg] = mk ? f2bf(h2) : hr[(size_t)b*512 + dg];
    h2all[((size_t)t*NB + b)*512 + dg] = f2bf(h2);
  }
}

// ---------------- launcher ----------------
extern "C" void kernel_launch(void* const* d_in, const int* in_sizes, int n_in,
                              void* d_out, int out_size, void* d_ws, size_t ws_size,
                              hipStream_t stream){
  (void)in_sizes; (void)n_in; (void)out_size; (void)ws_size;
  const float* encoder_out      = (const float*)d_in[0];
  const int*   encoded_captions = (const int*)d_in[1];
  const int*   caption_lengths  = (const int*)d_in[2];
  const float* W_ea = (const float*)d_in[3];  const float* b_ea = (const float*)d_in[4];
  const float* W_da = (const float*)d_in[5];  const float* b_da = (const float*)d_in[6];
  const float* w_fa = (const float*)d_in[7];  const float* b_fa = (const float*)d_in[8];
  const float* emb_table = (const float*)d_in[9];
  const float* W_ih = (const float*)d_in[10]; const float* b_ih = (const float*)d_in[11];
  const float* W_hh = (const float*)d_in[12]; const float* b_hh = (const float*)d_in[13];
  const float* W_init_h = (const float*)d_in[14]; const float* b_init_h = (const float*)d_in[15];
  const float* W_init_c = (const float*)d_in[16]; const float* b_init_c = (const float*)d_in[17];
  const float* W_fb = (const float*)d_in[18]; const float* b_fb = (const float*)d_in[19];
  const float* W_fc = (const float*)d_in[20]; const float* b_fc = (const float*)d_in[21];

  // d_out layout (all f32): preds | caps | dec_len | alphas | order
  float* out_preds = (float*)d_out;
  float* out_caps  = out_preds + (size_t)NB*NT*NV;
  float* out_dlen  = out_caps + NB*NL;
  float* out_alph  = out_dlen + NB;
  float* out_order = out_alph + (size_t)NB*NT*NP;

  char* ws = (char*)d_ws;
  size_t off = 0;
  auto alloc = [&](size_t bytes)->size_t{ size_t r = off; off += (bytes + 255) & ~(size_t)255; return r; };
  bf16_t* enc_b   = (bf16_t*)(ws + alloc((size_t)12544*2048*2));
  char*   reg_att1 = ws + alloc((size_t)12544*512*2);       // att1_b; ipart overlaps (setup-only, pre-att1)
  bf16_t* att1_b  = (bf16_t*)reg_att1;
  float*  ipart   = (float*)reg_att1;
  char*   reg_h2   = ws + alloc((size_t)3328*512*2);        // h2all; Wea_b overlaps (setup-only)
  bf16_t* h2all_b = (bf16_t*)reg_h2;
  bf16_t* Wea_b   = (bf16_t*)reg_h2;
  bf16_t* Wdafb_b = (bf16_t*)(ws + alloc((size_t)2560*512*2));
  bf16_t* Wcat_b  = (bf16_t*)(ws + alloc((size_t)2048*3072*2));
  bf16_t* Wfc_b   = (bf16_t*)(ws + alloc((size_t)10000*512*2));
  char*   reg_wi  = ws + alloc((size_t)1024*2048*2);        // Winit (setup) / embAll (loop) overlap
  bf16_t* Winit_b = (bf16_t*)reg_wi;
  bf16_t* embAll  = (bf16_t*)reg_wi;                         // 51*64*512*2 = 3.34MB <= 4.19MB
  bf16_t* me_b    = (bf16_t*)(ws + alloc((size_t)64*2048*2));
  bf16_t* xh_awe  = (bf16_t*)(ws + alloc((size_t)64*2048*2));
  bf16_t* hbuf0   = (bf16_t*)(ws + alloc((size_t)64*512*2));
  bf16_t* hbuf1   = (bf16_t*)(ws + alloc((size_t)64*512*2));
  float*  c_f     = (float*)(ws + alloc((size_t)64*512*4));
  float*  a2gp_f  = (float*)(ws + alloc((size_t)8*64*2560*4));
  float*  e_f     = (float*)(ws + alloc((size_t)64*196*4));
  int*    order_i = (int*)(ws + alloc(64*4));
  int*    dlen_i  = (int*)(ws + alloc(64*4));
  int*    nact_i  = (int*)(ws + alloc(64*4));
  int*    caps_i  = (int*)(ws + alloc((size_t)64*52*4));

  k_sort<<<1,64,0,stream>>>(caption_lengths, encoded_captions, order_i, dlen_i, caps_i, nact_i,
                            out_caps, out_dlen, out_order);

  // merged conversions: enc + 8 weight regions, one dispatch
  CvtRegs R;
  int n4s[9];
  R.src[0] = encoder_out; R.dst[0] = enc_b;               n4s[0] = 12544*2048/4; R.cols4[0] = 512; R.dld[0] = 2048;
  R.src[1] = W_ea;      R.dst[1] = Wea_b;               n4s[1] = 512*2048/4;  R.cols4[1] = 512; R.dld[1] = 2048;
  R.src[2] = W_da;      R.dst[2] = Wdafb_b;             n4s[2] = 512*512/4;   R.cols4[2] = 128; R.dld[2] = 512;
  R.src[3] = W_fb;      R.dst[3] = Wdafb_b + 512*512;   n4s[3] = 2048*512/4;  R.cols4[3] = 128; R.dld[3] = 512;
  R.src[4] = W_ih;      R.dst[4] = Wcat_b;              n4s[4] = 2048*2560/4; R.cols4[4] = 640; R.dld[4] = 3072;
  R.src[5] = W_hh;      R.dst[5] = Wcat_b + 2560;       n4s[5] = 2048*512/4;  R.cols4[5] = 128; R.dld[5] = 3072;
  R.src[6] = W_init_h;  R.dst[6] = Winit_b;             n4s[6] = 512*2048/4;  R.cols4[6] = 512; R.dld[6] = 2048;
  R.src[7] = W_init_c;  R.dst[7] = Winit_b + 512*2048;  n4s[7] = 512*2048/4;  R.cols4[7] = 512; R.dld[7] = 2048;
  R.src[8] = W_fc;      R.dst[8] = Wfc_b;               n4s[8] = 10000*512/4; R.cols4[8] = 128; R.dld[8] = 512;
  R.start[0] = 0;
  for(int i=0;i<9;i++) R.start[i+1] = R.start[i] + n4s[i];
  k_cvtw<<<2048,256,0,stream>>>(R, R.start[9]);

  k_mean<<<dim3(64,8),256,0,stream>>>(enc_b, order_i, me_b);
  k_gemm_part<512><<<dim3(4,4),256,0,stream>>>(me_b, 2048, Winit_b, 2048, ipart, 1024);
  k_init_fin<<<128,256,0,stream>>>(ipart, b_init_h, b_init_c, c_f, hbuf0);
  // embAll overwrites Winit region — after init GEMM consumed Winit
  k_emb<<<dim3(NB,NT),256,0,stream>>>(caps_i, emb_table, embAll);
  // att1: XCD-swizzled 1D grid 392
  k_big<0><<<392,256,0,stream>>>(enc_b, 2048, 2048, Wea_b, 512, b_ea, nullptr, att1_b, nullptr);
  // initial a2g partials from h0 (8-way K-split)
  k_gemm_part<64><<<dim3(10,8),256,0,stream>>>(hbuf0, 512, Wdafb_b, 512, a2gp_f, 2560);

  bf16_t* hb[2] = { hbuf0, hbuf1 };
  for(int t=0;t<NT;t++){
    bf16_t* hr = hb[t&1];
    bf16_t* hw = hb[(t&1)^1];
    k_e<<<dim3(64,4),512,0,stream>>>(att1_b, a2gp_f, b_da, w_fa, b_fa, order_i, nact_i, e_f, t);
    k_awe<<<dim3(64,4),512,0,stream>>>(enc_b, e_f, a2gp_f, b_fb, order_i, nact_i,
                                       out_alph, xh_awe, t);
    k_gatecell<<<256,512,0,stream>>>(embAll + (size_t)t*NB*512, xh_awe, hr, hw, Wcat_b,
                                     b_ih, b_hh, c_f, h2all_b, dlen_i, t);
    k_gemm_part<64><<<dim3(10,8),256,0,stream>>>(hw, 512, Wdafb_b, 512, a2gp_f, 2560);
  }
  // deferred preds GEMM: XCD-swizzled 1D grid 2054
  k_big<2><<<2054,256,0,stream>>>(h2all_b, 512, 512, Wfc_b, NV, b_fc, out_preds, nullptr, dlen_i);
}